// Round 2
// 2099.111 us; speedup vs baseline: 1.1472x; 1.1472x over previous
//
#include <hip/hip_runtime.h>
#include <math.h>

typedef unsigned int uint32;
typedef unsigned short ushort_t;

typedef __attribute__((ext_vector_type(8))) short short8;
typedef __attribute__((ext_vector_type(4))) float floatx4;

#define SEQL 2048
#define DIMC 768
#define NHEAD 12
#define HDIM 64
#define HIDV 2042
#define HIDP 2048
#define NVOCAB 32000
#define QSZ (DIMC*DIMC)      // 589824
#define PSZ (HIDP*DIMC)      // 1572864
#define W2SRC (DIMC*HIDV)    // 1568256

__device__ __forceinline__ ushort_t f2bf(float f) {
    uint32 u = __float_as_uint(f);
    u += 0x7FFFu + ((u >> 16) & 1u);   // round-to-nearest-even
    return (ushort_t)(u >> 16);
}
__device__ __forceinline__ float bf2f(ushort_t h) {
    return __uint_as_float(((uint32)h) << 16);
}

union Frag { short8 s8; uint32 u[4]; ushort_t us[8]; };

// async global->LDS 16B copy (dest must be linear in lane order within wave)
#define GLOAD_LDS16(g, l) \
    __builtin_amdgcn_global_load_lds((const __attribute__((address_space(1))) void*)(g), \
                                     (__attribute__((address_space(3))) void*)(l), 16, 0, 0)

// ---------------- GEMM: C[M,N] (=|+=) A[M,K] * B[N,K]^T, bf16 inputs -------
// OUTMODE: 0 = store f32, 1 = store bf16, 2 = accumulate into f32 (residual)
// Direct-global variant (small-N shapes; keeps 384-block grids for occupancy)
template<int WTM, int WTN, int WVM, int WVN, int OUTMODE>
__global__ __launch_bounds__(WVM*WVN*64)
void gemm_kernel(const ushort_t* __restrict__ A, int lda,
                 const ushort_t* __restrict__ B, int ldb,
                 void* __restrict__ C, int ldc, int K)
{
    const int wid  = threadIdx.x >> 6;
    const int lane = threadIdx.x & 63;
    const int wm = wid % WVM, wn = wid / WVM;
    const int r = lane & 15, quad = lane >> 4;
    const int m0 = blockIdx.x * (WVM*WTM*16) + wm * (WTM*16);
    const int n0 = blockIdx.y * (WVN*WTN*16) + wn * (WTN*16);

    floatx4 acc[WTM][WTN];
#pragma unroll
    for (int i = 0; i < WTM; ++i)
#pragma unroll
        for (int j = 0; j < WTN; ++j)
            acc[i][j] = (floatx4){0.f, 0.f, 0.f, 0.f};

    const ushort_t* Ap = A + (size_t)(m0 + r) * lda + quad * 8;
    const ushort_t* Bp = B + (size_t)(n0 + r) * ldb + quad * 8;
    for (int k0 = 0; k0 < K; k0 += 32) {
        short8 af[WTM], bfr[WTN];
#pragma unroll
        for (int i = 0; i < WTM; ++i) af[i] = *(const short8*)(Ap + (size_t)i * 16 * lda);
#pragma unroll
        for (int j = 0; j < WTN; ++j) bfr[j] = *(const short8*)(Bp + (size_t)j * 16 * ldb);
#pragma unroll
        for (int i = 0; i < WTM; ++i)
#pragma unroll
            for (int j = 0; j < WTN; ++j)
                acc[i][j] = __builtin_amdgcn_mfma_f32_16x16x32_bf16(af[i], bfr[j], acc[i][j], 0, 0, 0);
        Ap += 32; Bp += 32;
    }

#pragma unroll
    for (int i = 0; i < WTM; ++i) {
#pragma unroll
        for (int j = 0; j < WTN; ++j) {
#pragma unroll
            for (int t = 0; t < 4; ++t) {
                const int row = m0 + i * 16 + quad * 4 + t;   // C/D: row=quad*4+reg
                const int col = n0 + j * 16 + r;              //      col=lane&15
                const size_t off = (size_t)row * ldc + col;
                const float v = acc[i][j][t];
                if (OUTMODE == 2)      ((float*)C)[off] += v;
                else if (OUTMODE == 1) ((ushort_t*)C)[off] = f2bf(v);
                else                   ((float*)C)[off] = v;
            }
        }
    }
}

// ---------------- LDS-staged GEMM (m97 structure): 128x128 tile, BK=32 -----
// 4 waves (2x2), each wave 64x64 = 4x4 16x16 frags. global_load_lds dwordx4
// staging, single LDS buffer, 2 barriers per K-step. ~900 TF class.
// Requires M%128==0, N%128==0, K%32==0. Use only where grid >= ~256 blocks.
template<int OUTMODE>
__global__ __launch_bounds__(256)
void gemm_lds_kernel(const ushort_t* __restrict__ A, int lda,
                     const ushort_t* __restrict__ B, int ldb,
                     void* __restrict__ C, int ldc, int K)
{
    __shared__ __align__(16) ushort_t As[128 * 32];   // rows m0..m0+127, k0..k0+31
    __shared__ __align__(16) ushort_t Bs[128 * 32];   // rows n0..n0+127
    const int tid  = threadIdx.x;
    const int wid  = tid >> 6, lane = tid & 63;
    const int wm = wid & 1, wn = wid >> 1;
    const int r = lane & 15, quad = lane >> 4;
    const int m0 = blockIdx.x * 128;
    const int n0 = blockIdx.y * 128;

    floatx4 acc[4][4];
#pragma unroll
    for (int i = 0; i < 4; ++i)
#pragma unroll
        for (int j = 0; j < 4; ++j) acc[i][j] = (floatx4){0.f, 0.f, 0.f, 0.f};

    // staging: chunk c (16B) covers LDS bytes [c*16, c*16+16) = row c/4, cols (c%4)*8..+7
    // thread tid owns chunks tid and tid+256 -> per-wave LDS dests are base + lane*16 (linear)
    const int row_a = tid >> 2;
    const int col8  = (tid & 3) * 8;
    const ushort_t* gA0 = A + (size_t)(m0 + row_a) * lda + col8;
    const ushort_t* gA1 = A + (size_t)(m0 + 64 + row_a) * lda + col8;
    const ushort_t* gB0 = B + (size_t)(n0 + row_a) * ldb + col8;
    const ushort_t* gB1 = B + (size_t)(n0 + 64 + row_a) * ldb + col8;
    ushort_t* lA0 = &As[(size_t)tid * 8];
    ushort_t* lA1 = &As[(size_t)(tid + 256) * 8];
    ushort_t* lB0 = &Bs[(size_t)tid * 8];
    ushort_t* lB1 = &Bs[(size_t)(tid + 256) * 8];

    const ushort_t* pa = &As[(wm * 64 + r) * 32 + quad * 8];
    const ushort_t* pb = &Bs[(wn * 64 + r) * 32 + quad * 8];

    for (int k0 = 0; k0 < K; k0 += 32) {
        GLOAD_LDS16(gA0, lA0); GLOAD_LDS16(gA1, lA1);
        GLOAD_LDS16(gB0, lB0); GLOAD_LDS16(gB1, lB1);
        gA0 += 32; gA1 += 32; gB0 += 32; gB1 += 32;
        __syncthreads();   // drains vmcnt(0): LDS tile ready
        short8 af[4], bf[4];
#pragma unroll
        for (int i = 0; i < 4; ++i) af[i] = *(const short8*)(pa + i * 16 * 32);
#pragma unroll
        for (int j = 0; j < 4; ++j) bf[j] = *(const short8*)(pb + j * 16 * 32);
#pragma unroll
        for (int i = 0; i < 4; ++i)
#pragma unroll
            for (int j = 0; j < 4; ++j)
                acc[i][j] = __builtin_amdgcn_mfma_f32_16x16x32_bf16(af[i], bf[j], acc[i][j], 0, 0, 0);
        __syncthreads();   // protect LDS before next iteration's stores
    }

#pragma unroll
    for (int i = 0; i < 4; ++i) {
        const int row = m0 + wm * 64 + i * 16 + quad * 4;
#pragma unroll
        for (int j = 0; j < 4; ++j) {
            const int col = n0 + wn * 64 + j * 16 + r;
#pragma unroll
            for (int t = 0; t < 4; ++t) {
                const size_t off = (size_t)(row + t) * ldc + col;
                const float v = acc[i][j][t];
                if (OUTMODE == 2)      ((float*)C)[off] += v;
                else if (OUTMODE == 1) ((ushort_t*)C)[off] = f2bf(v);
                else                   ((float*)C)[off] = v;
            }
        }
    }
}

// ---------------- RMSNorm: fp32 in -> bf16 out, one wave per row -----------
__global__ __launch_bounds__(256)
void rmsnorm_kernel(const float* __restrict__ x, const float* __restrict__ g,
                    ushort_t* __restrict__ out)
{
    const int w = threadIdx.x >> 6, lane = threadIdx.x & 63;
    const int row = blockIdx.x * 4 + w;
    const float* xr = x + (size_t)row * DIMC;
    float4 a = *(const float4*)(xr + lane * 4);
    float4 b = *(const float4*)(xr + 256 + lane * 4);
    float4 c = *(const float4*)(xr + 512 + lane * 4);
    float ss = a.x*a.x + a.y*a.y + a.z*a.z + a.w*a.w
             + b.x*b.x + b.y*b.y + b.z*b.z + b.w*b.w
             + c.x*c.x + c.y*c.y + c.z*c.z + c.w*c.w;
#pragma unroll
    for (int off = 32; off > 0; off >>= 1) ss += __shfl_xor(ss, off, 64);
    const float inv = rsqrtf(ss * (1.0f / DIMC) + 1e-6f);
    float4 ga = *(const float4*)(g + lane * 4);
    float4 gb = *(const float4*)(g + 256 + lane * 4);
    float4 gc = *(const float4*)(g + 512 + lane * 4);
    ushort_t* orow = out + (size_t)row * DIMC;
    *(ushort4*)(orow + lane * 4)       = make_ushort4(f2bf(a.x*inv*ga.x), f2bf(a.y*inv*ga.y), f2bf(a.z*inv*ga.z), f2bf(a.w*inv*ga.w));
    *(ushort4*)(orow + 256 + lane * 4) = make_ushort4(f2bf(b.x*inv*gb.x), f2bf(b.y*inv*gb.y), f2bf(b.z*inv*gb.z), f2bf(b.w*inv*gb.w));
    *(ushort4*)(orow + 512 + lane * 4) = make_ushort4(f2bf(c.x*inv*gc.x), f2bf(c.y*inv*gc.y), f2bf(c.z*inv*gc.z), f2bf(c.w*inv*gc.w));
}

// ---------------- RoPE in-place on bf16 [S,12,64] --------------------------
__global__ __launch_bounds__(256)
void rope_kernel(ushort_t* __restrict__ x)
{
    const int idx = blockIdx.x * 256 + threadIdx.x;   // SEQL*NHEAD*32
    const int j = idx & 31;
    const int h = (idx >> 5) % NHEAD;
    const int s = idx / (32 * NHEAD);
    const float freq = expf(-0.28782313662425574f * (float)j);
    const float ang = (float)s * freq;
    const float sn = sinf(ang), cs = cosf(ang);
    ushort_t* p = x + (size_t)s * DIMC + h * HDIM + 2 * j;
    const float a = bf2f(p[0]), b = bf2f(p[1]);
    p[0] = f2bf(a * cs - b * sn);
    p[1] = f2bf(a * sn + b * cs);
}

// ---------------- MFMA flash attention (S^T trick, no LDS, no barriers) ----
__global__ __launch_bounds__(256)
void attn_mfma_kernel(const ushort_t* __restrict__ Q, const ushort_t* __restrict__ K,
                      const ushort_t* __restrict__ VT, ushort_t* __restrict__ O)
{
    const int w = threadIdx.x >> 6, lane = threadIdx.x & 63;
    const int r = lane & 15, quad = lane >> 4;
    const int hb = blockIdx.y * HDIM;
    const int qb = blockIdx.x * 64 + w * 16;

    Frag bq[2];
    {
        const ushort_t* qp = Q + (size_t)(qb + r) * DIMC + hb + quad * 8;
#pragma unroll
        for (int fi = 0; fi < 2; ++fi) {
            Frag t; t.s8 = *(const short8*)(qp + fi * 32);
#pragma unroll
            for (int e = 0; e < 8; ++e) t.us[e] = f2bf(bf2f(t.us[e]) * 0.125f);
            bq[fi] = t;
        }
    }

    floatx4 o[4];
#pragma unroll
    for (int dg = 0; dg < 4; ++dg) o[dg] = (floatx4){0.f, 0.f, 0.f, 0.f};
    float m = -INFINITY, l = 0.f;

    const int kend = qb + 16;
    for (int kc = 0; kc < kend; kc += 32) {
        const ushort_t* kp = K + (size_t)(kc + r) * DIMC + hb + quad * 8;
        const short8 ak00 = *(const short8*)(kp);
        const short8 ak01 = *(const short8*)(kp + 32);
        const short8 ak10 = *(const short8*)(kp + (size_t)16 * DIMC);
        const short8 ak11 = *(const short8*)(kp + (size_t)16 * DIMC + 32);

        floatx4 st0 = (floatx4){0.f, 0.f, 0.f, 0.f};
        floatx4 st1 = (floatx4){0.f, 0.f, 0.f, 0.f};
        st0 = __builtin_amdgcn_mfma_f32_16x16x32_bf16(ak00, bq[0].s8, st0, 0, 0, 0);
        st0 = __builtin_amdgcn_mfma_f32_16x16x32_bf16(ak01, bq[1].s8, st0, 0, 0, 0);
        st1 = __builtin_amdgcn_mfma_f32_16x16x32_bf16(ak10, bq[0].s8, st1, 0, 0, 0);
        st1 = __builtin_amdgcn_mfma_f32_16x16x32_bf16(ak11, bq[1].s8, st1, 0, 0, 0);

        if (kc + 31 > qb) {
            const int q = qb + r;
#pragma unroll
            for (int t = 0; t < 4; ++t) {
                if (kc + quad * 4 + t > q)      st0[t] = -INFINITY;
                if (kc + 16 + quad * 4 + t > q) st1[t] = -INFINITY;
            }
        }

        float vm = fmaxf(fmaxf(fmaxf(st0[0], st0[1]), fmaxf(st0[2], st0[3])),
                         fmaxf(fmaxf(st1[0], st1[1]), fmaxf(st1[2], st1[3])));
        vm = fmaxf(vm, __shfl_xor(vm, 16, 64));
        vm = fmaxf(vm, __shfl_xor(vm, 32, 64));
        const float mnew = fmaxf(m, vm);
        const float alpha = __expf(m - mnew);
        const float p0 = __expf(st0[0] - mnew), p1 = __expf(st0[1] - mnew);
        const float p2 = __expf(st0[2] - mnew), p3 = __expf(st0[3] - mnew);
        const float p4 = __expf(st1[0] - mnew), p5 = __expf(st1[1] - mnew);
        const float p6 = __expf(st1[2] - mnew), p7 = __expf(st1[3] - mnew);
        float ps = ((p0 + p1) + (p2 + p3)) + ((p4 + p5) + (p6 + p7));
        ps += __shfl_xor(ps, 16, 64);
        ps += __shfl_xor(ps, 32, 64);
        l = l * alpha + ps;
        m = mnew;

        Frag ap;
        ap.u[0] = (uint32)f2bf(p0) | ((uint32)f2bf(p1) << 16);
        ap.u[1] = (uint32)f2bf(p2) | ((uint32)f2bf(p3) << 16);
        ap.u[2] = (uint32)f2bf(p4) | ((uint32)f2bf(p5) << 16);
        ap.u[3] = (uint32)f2bf(p6) | ((uint32)f2bf(p7) << 16);

#pragma unroll
        for (int dg = 0; dg < 4; ++dg) {
            const ushort_t* vp = VT + (size_t)(hb + dg * 16 + r) * SEQL + kc + quad * 4;
            Frag av;
            const uint2 v0 = *(const uint2*)(vp);
            const uint2 v1 = *(const uint2*)(vp + 16);
            av.u[0] = v0.x; av.u[1] = v0.y; av.u[2] = v1.x; av.u[3] = v1.y;
            o[dg] *= alpha;
            o[dg] = __builtin_amdgcn_mfma_f32_16x16x32_bf16(av.s8, ap.s8, o[dg], 0, 0, 0);
        }
    }

    const float inv = 1.0f / l;
    ushort_t* op = O + (size_t)(qb + r) * DIMC + hb + quad * 4;
#pragma unroll
    for (int dg = 0; dg < 4; ++dg) {
        uint2 pkd;
        pkd.x = (uint32)f2bf(o[dg][0] * inv) | ((uint32)f2bf(o[dg][1] * inv) << 16);
        pkd.y = (uint32)f2bf(o[dg][2] * inv) | ((uint32)f2bf(o[dg][3] * inv) << 16);
        *(uint2*)(op + dg * 16) = pkd;
    }
}

// ---------------- SiLU(y1) * y3 -> bf16, fused Y13 layout [2048][4096] -----
// cols 0..2047 = y1, cols 2048..4095 = y3 (padded cols give silu(0)*0 = 0)
__global__ __launch_bounds__(256)
void silu_mul_kernel(const float* __restrict__ y13, ushort_t* __restrict__ hs)
{
    const int idx = blockIdx.x * 256 + threadIdx.x;   // 2048*512
    const int s = idx >> 9;
    const int c = (idx & 511) * 4;
    const float* row = y13 + (size_t)s * 4096;
    float4 a = *(const float4*)(row + c);
    float4 b = *(const float4*)(row + 2048 + c);
    float4 r;
    r.x = a.x / (1.f + __expf(-a.x)) * b.x;
    r.y = a.y / (1.f + __expf(-a.y)) * b.y;
    r.z = a.z / (1.f + __expf(-a.z)) * b.z;
    r.w = a.w / (1.f + __expf(-a.w)) * b.w;
    *(ushort4*)(hs + (size_t)s * HIDP + c) = make_ushort4(f2bf(r.x), f2bf(r.y), f2bf(r.z), f2bf(r.w));
}

// ---------------- Embedding gather (fp32) ----------------------------------
__global__ __launch_bounds__(256)
void embed_kernel(const int* __restrict__ tok, const float* __restrict__ emb,
                  float* __restrict__ h)
{
    const int idx = blockIdx.x * 256 + threadIdx.x;    // SEQL*192
    const int s = idx / 192, c = (idx % 192) * 4;
    const int t = tok[s];
    *(float4*)(h + (size_t)s * DIMC + c) = *(const float4*)(emb + (size_t)t * DIMC + c);
}

// ---------------- Per-layer weight conversion fp32 -> bf16 (with padding) --
__global__ __launch_bounds__(256)
void conv_layer_kernel(const float* __restrict__ wq, const float* __restrict__ wk,
                       const float* __restrict__ wv, const float* __restrict__ wo,
                       const float* __restrict__ w1, const float* __restrict__ w2,
                       const float* __restrict__ w3,
                       ushort_t* __restrict__ wqb, ushort_t* __restrict__ wkb,
                       ushort_t* __restrict__ wvb, ushort_t* __restrict__ wob,
                       ushort_t* __restrict__ w1p, ushort_t* __restrict__ w3p,
                       ushort_t* __restrict__ w2p)
{
    int idx = blockIdx.x * 256 + threadIdx.x;
    if (idx < 4 * QSZ) {
        const int m = idx / QSZ, i = idx - m * QSZ;
        const float* s = (m == 0) ? wq : (m == 1) ? wk : (m == 2) ? wv : wo;
        ushort_t*   d = (m == 0) ? wqb : (m == 1) ? wkb : (m == 2) ? wvb : wob;
        d[i] = f2bf(s[i]);
        return;
    }
    idx -= 4 * QSZ;
    if (idx < PSZ) {   // w1 padded: [2048][768], rows >= 2042 zero
        const int n = idx / DIMC, kk = idx - n * DIMC;
        w1p[idx] = (n < HIDV) ? f2bf(w1[(size_t)n * DIMC + kk]) : (ushort_t)0;
        return;
    }
    idx -= PSZ;
    if (idx < PSZ) {
        const int n = idx / DIMC, kk = idx - n * DIMC;
        w3p[idx] = (n < HIDV) ? f2bf(w3[(size_t)n * DIMC + kk]) : (ushort_t)0;
        return;
    }
    idx -= PSZ;
    if (idx < PSZ) {   // w2 padded: [768][2048], cols >= 2042 zero
        const int n = idx >> 11, kk = idx & 2047;
        w2p[idx] = (kk < HIDV) ? f2bf(w2[(size_t)n * HIDV + kk]) : (ushort_t)0;
        return;
    }
}

// ---------------- out_w conversion fp32 -> bf16 ----------------------------
__global__ __launch_bounds__(256)
void conv_outw_kernel(const float* __restrict__ src, ushort_t* __restrict__ dst)
{
    const size_t idx = (size_t)(blockIdx.x * 256 + threadIdx.x);
    float4 a = *(const float4*)(src + idx * 4);
    *(ushort4*)(dst + idx * 4) = make_ushort4(f2bf(a.x), f2bf(a.y), f2bf(a.z), f2bf(a.w));
}

extern "C" void kernel_launch(void* const* d_in, const int* in_sizes, int n_in,
                              void* d_out, int out_size, void* d_ws, size_t ws_size,
                              hipStream_t stream)
{
    const int*   tok  = (const int*)d_in[0];
    const float* emb  = (const float*)d_in[1];
    const float* wq   = (const float*)d_in[2];
    const float* wk   = (const float*)d_in[3];
    const float* wv   = (const float*)d_in[4];
    const float* wo   = (const float*)d_in[5];
    const float* w1   = (const float*)d_in[6];
    const float* w2   = (const float*)d_in[7];
    const float* w3   = (const float*)d_in[8];
    const float* anw  = (const float*)d_in[9];
    const float* fnw  = (const float*)d_in[10];
    const float* nw   = (const float*)d_in[11];
    const float* outw = (const float*)d_in[12];
    float* out = (float*)d_out;
    (void)in_sizes; (void)n_in; (void)out_size; (void)ws_size;

    char* p = (char*)d_ws;
    auto alloc = [&](size_t bytes) { char* r = p; p += (bytes + 255) & ~(size_t)255; return r; };
    float*    H   = (float*)   alloc((size_t)SEQL * DIMC * 4);
    ushort_t* XN  = (ushort_t*)alloc((size_t)SEQL * DIMC * 2);
    ushort_t* YN  = (ushort_t*)alloc((size_t)SEQL * DIMC * 2);
    ushort_t* WQB = (ushort_t*)alloc((size_t)QSZ * 2);
    ushort_t* WKB = (ushort_t*)alloc((size_t)QSZ * 2);
    ushort_t* WVB = (ushort_t*)alloc((size_t)QSZ * 2);
    ushort_t* WOB = (ushort_t*)alloc((size_t)QSZ * 2);
    // W1P and W3P MUST stay adjacent: fused FFN-up GEMM treats them as one
    // [4096][768] B matrix (PSZ*2 bytes is 256-aligned so no gap).
    ushort_t* W1P = (ushort_t*)alloc((size_t)PSZ * 2);
    ushort_t* W3P = (ushort_t*)alloc((size_t)PSZ * 2);
    ushort_t* W2P = (ushort_t*)alloc((size_t)PSZ * 2);
    // region below is reused late as bf16 out_w (52 MB >= 49.15 MB)
    ushort_t* QB  = (ushort_t*)alloc((size_t)SEQL * DIMC * 2);
    ushort_t* KB  = (ushort_t*)alloc((size_t)SEQL * DIMC * 2);
    ushort_t* VTG = (ushort_t*)alloc((size_t)SEQL * DIMC * 2);  // V^T [DIMC][SEQL]
    ushort_t* AO  = (ushort_t*)alloc((size_t)SEQL * DIMC * 2);
    float*    Y13 = (float*)   alloc((size_t)SEQL * 4096 * 4);  // [2048][4096] y1|y3
    ushort_t* HS  = (ushort_t*)alloc((size_t)SEQL * HIDP * 2);
    ushort_t* OUTWB = QB;  // aliased, used only after last layer

    embed_kernel<<<1536, 256, 0, stream>>>(tok, emb, H);

    for (int l = 0; l < 4; ++l) {
        conv_layer_kernel<<<27648, 256, 0, stream>>>(
            wq + (size_t)l * QSZ, wk + (size_t)l * QSZ, wv + (size_t)l * QSZ, wo + (size_t)l * QSZ,
            w1 + (size_t)l * W2SRC, w2 + (size_t)l * W2SRC, w3 + (size_t)l * W2SRC,
            WQB, WKB, WVB, WOB, W1P, W3P, W2P);

        rmsnorm_kernel<<<512, 256, 0, stream>>>(H, anw + (size_t)l * DIMC, XN);

        // Q,K projections (bf16 out): M=2048 N=768 K=768, 64x64 tiles
        gemm_kernel<2,2,2,2,1><<<dim3(32,12), 256, 0, stream>>>(XN, DIMC, WQB, DIMC, QB, DIMC, DIMC);
        gemm_kernel<2,2,2,2,1><<<dim3(32,12), 256, 0, stream>>>(XN, DIMC, WKB, DIMC, KB, DIMC, DIMC);
        // V^T projection (swapped operands): C[d][s] = sum_k Wv[d][k] X[s][k]
        gemm_kernel<2,2,2,2,1><<<dim3(12,32), 256, 0, stream>>>(WVB, DIMC, XN, DIMC, VTG, SEQL, DIMC);

        rope_kernel<<<3072, 256, 0, stream>>>(QB);
        rope_kernel<<<3072, 256, 0, stream>>>(KB);

        attn_mfma_kernel<<<dim3(32, NHEAD), 256, 0, stream>>>(QB, KB, VTG, AO);

        // o @ wo^T, accumulate into H (residual)
        gemm_kernel<2,2,2,2,2><<<dim3(32,12), 256, 0, stream>>>(AO, DIMC, WOB, DIMC, H, DIMC, DIMC);

        rmsnorm_kernel<<<512, 256, 0, stream>>>(H, fnw + (size_t)l * DIMC, YN);

        // FFN up, FUSED w1|w3: M=2048 N=4096 K=768, LDS-staged 128x128 tiles
        gemm_lds_kernel<0><<<dim3(16,32), 256, 0, stream>>>(YN, DIMC, W1P, DIMC, Y13, 4096, DIMC);

        silu_mul_kernel<<<4096, 256, 0, stream>>>(Y13, HS);

        // FFN down: M=2048 N=768 K=2048(pad), accumulate into H
        gemm_kernel<2,2,2,2,2><<<dim3(32,12), 256, 0, stream>>>(HS, HIDP, W2P, HIDP, H, DIMC, HIDP);
    }

    rmsnorm_kernel<<<512, 256, 0, stream>>>(H, nw, XN);
    conv_outw_kernel<<<24000, 256, 0, stream>>>(outw, OUTWB);
    // logits: M=2048 N=32000 K=768, LDS-staged 128x128 tiles, f32 out
    gemm_lds_kernel<0><<<dim3(16,250), 256, 0, stream>>>(XN, DIMC, OUTWB, DIMC, out, NVOCAB, DIMC);
}

// Round 3
// 1633.097 us; speedup vs baseline: 1.4746x; 1.2854x over previous
//
#include <hip/hip_runtime.h>
#include <math.h>

typedef unsigned int uint32;
typedef unsigned short ushort_t;

typedef __attribute__((ext_vector_type(8))) short short8;
typedef __attribute__((ext_vector_type(4))) float floatx4;

#define SEQL 2048
#define DIMC 768
#define NHEAD 12
#define HDIM 64
#define HIDV 2042
#define HIDP 2048
#define NVOCAB 32000
#define QSZ (DIMC*DIMC)      // 589824
#define PSZ (HIDP*DIMC)      // 1572864
#define W2SRC (DIMC*HIDV)    // 1568256

__device__ __forceinline__ ushort_t f2bf(float f) {
    uint32 u = __float_as_uint(f);
    u += 0x7FFFu + ((u >> 16) & 1u);   // round-to-nearest-even
    return (ushort_t)(u >> 16);
}
__device__ __forceinline__ float bf2f(ushort_t h) {
    return __uint_as_float(((uint32)h) << 16);
}

union Frag { short8 s8; uint32 u[4]; ushort_t us[8]; };

// async global->LDS 16B copy (dest must be linear in lane order within wave)
#define GLOAD_LDS16(g, l) \
    __builtin_amdgcn_global_load_lds((const __attribute__((address_space(1))) void*)(g), \
                                     (__attribute__((address_space(3))) void*)(l), 16, 0, 0)

// ---------------- GEMM: C[M,N] (=|+=) A[M,K] * B[N,K]^T, bf16 inputs -------
// OUTMODE: 0 = store f32, 1 = store bf16, 2 = accumulate into f32 (residual)
// Direct-global variant (small-N shapes; keeps 384-block grids for occupancy)
template<int WTM, int WTN, int WVM, int WVN, int OUTMODE>
__global__ __launch_bounds__(WVM*WVN*64)
void gemm_kernel(const ushort_t* __restrict__ A, int lda,
                 const ushort_t* __restrict__ B, int ldb,
                 void* __restrict__ C, int ldc, int K)
{
    const int wid  = threadIdx.x >> 6;
    const int lane = threadIdx.x & 63;
    const int wm = wid % WVM, wn = wid / WVM;
    const int r = lane & 15, quad = lane >> 4;
    const int m0 = blockIdx.x * (WVM*WTM*16) + wm * (WTM*16);
    const int n0 = blockIdx.y * (WVN*WTN*16) + wn * (WTN*16);

    floatx4 acc[WTM][WTN];
#pragma unroll
    for (int i = 0; i < WTM; ++i)
#pragma unroll
        for (int j = 0; j < WTN; ++j)
            acc[i][j] = (floatx4){0.f, 0.f, 0.f, 0.f};

    const ushort_t* Ap = A + (size_t)(m0 + r) * lda + quad * 8;
    const ushort_t* Bp = B + (size_t)(n0 + r) * ldb + quad * 8;
    for (int k0 = 0; k0 < K; k0 += 32) {
        short8 af[WTM], bfr[WTN];
#pragma unroll
        for (int i = 0; i < WTM; ++i) af[i] = *(const short8*)(Ap + (size_t)i * 16 * lda);
#pragma unroll
        for (int j = 0; j < WTN; ++j) bfr[j] = *(const short8*)(Bp + (size_t)j * 16 * ldb);
#pragma unroll
        for (int i = 0; i < WTM; ++i)
#pragma unroll
            for (int j = 0; j < WTN; ++j)
                acc[i][j] = __builtin_amdgcn_mfma_f32_16x16x32_bf16(af[i], bfr[j], acc[i][j], 0, 0, 0);
        Ap += 32; Bp += 32;
    }

#pragma unroll
    for (int i = 0; i < WTM; ++i) {
#pragma unroll
        for (int j = 0; j < WTN; ++j) {
#pragma unroll
            for (int t = 0; t < 4; ++t) {
                const int row = m0 + i * 16 + quad * 4 + t;   // C/D: row=quad*4+reg
                const int col = n0 + j * 16 + r;              //      col=lane&15
                const size_t off = (size_t)row * ldc + col;
                const float v = acc[i][j][t];
                if (OUTMODE == 2)      ((float*)C)[off] += v;
                else if (OUTMODE == 1) ((ushort_t*)C)[off] = f2bf(v);
                else                   ((float*)C)[off] = v;
            }
        }
    }
}

// ---------------- LDS-staged GEMM (m97 structure): 128x128 tile, BK=32 -----
// 4 waves (2x2), each wave 64x64 = 4x4 16x16 frags. global_load_lds dwordx4
// staging, single LDS buffer, 2 barriers per K-step. ~900 TF class.
// Requires M%128==0, N%128==0, K%32==0. Use only where grid >= ~256 blocks.
template<int OUTMODE>
__global__ __launch_bounds__(256)
void gemm_lds_kernel(const ushort_t* __restrict__ A, int lda,
                     const ushort_t* __restrict__ B, int ldb,
                     void* __restrict__ C, int ldc, int K)
{
    __shared__ __align__(16) ushort_t As[128 * 32];   // rows m0..m0+127, k0..k0+31
    __shared__ __align__(16) ushort_t Bs[128 * 32];   // rows n0..n0+127
    const int tid  = threadIdx.x;
    const int wid  = tid >> 6, lane = tid & 63;
    const int wm = wid & 1, wn = wid >> 1;
    const int r = lane & 15, quad = lane >> 4;
    const int m0 = blockIdx.x * 128;
    const int n0 = blockIdx.y * 128;

    floatx4 acc[4][4];
#pragma unroll
    for (int i = 0; i < 4; ++i)
#pragma unroll
        for (int j = 0; j < 4; ++j) acc[i][j] = (floatx4){0.f, 0.f, 0.f, 0.f};

    // staging: chunk c (16B) covers LDS bytes [c*16, c*16+16) = row c/4, cols (c%4)*8..+7
    // thread tid owns chunks tid and tid+256 -> per-wave LDS dests are base + lane*16 (linear)
    const int row_a = tid >> 2;
    const int col8  = (tid & 3) * 8;
    const ushort_t* gA0 = A + (size_t)(m0 + row_a) * lda + col8;
    const ushort_t* gA1 = A + (size_t)(m0 + 64 + row_a) * lda + col8;
    const ushort_t* gB0 = B + (size_t)(n0 + row_a) * ldb + col8;
    const ushort_t* gB1 = B + (size_t)(n0 + 64 + row_a) * ldb + col8;
    ushort_t* lA0 = &As[(size_t)tid * 8];
    ushort_t* lA1 = &As[(size_t)(tid + 256) * 8];
    ushort_t* lB0 = &Bs[(size_t)tid * 8];
    ushort_t* lB1 = &Bs[(size_t)(tid + 256) * 8];

    const ushort_t* pa = &As[(wm * 64 + r) * 32 + quad * 8];
    const ushort_t* pb = &Bs[(wn * 64 + r) * 32 + quad * 8];

    for (int k0 = 0; k0 < K; k0 += 32) {
        GLOAD_LDS16(gA0, lA0); GLOAD_LDS16(gA1, lA1);
        GLOAD_LDS16(gB0, lB0); GLOAD_LDS16(gB1, lB1);
        gA0 += 32; gA1 += 32; gB0 += 32; gB1 += 32;
        __syncthreads();   // drains vmcnt(0): LDS tile ready
        short8 af[4], bf[4];
#pragma unroll
        for (int i = 0; i < 4; ++i) af[i] = *(const short8*)(pa + i * 16 * 32);
#pragma unroll
        for (int j = 0; j < 4; ++j) bf[j] = *(const short8*)(pb + j * 16 * 32);
#pragma unroll
        for (int i = 0; i < 4; ++i)
#pragma unroll
            for (int j = 0; j < 4; ++j)
                acc[i][j] = __builtin_amdgcn_mfma_f32_16x16x32_bf16(af[i], bf[j], acc[i][j], 0, 0, 0);
        __syncthreads();   // protect LDS before next iteration's stores
    }

#pragma unroll
    for (int i = 0; i < 4; ++i) {
        const int row = m0 + wm * 64 + i * 16 + quad * 4;
#pragma unroll
        for (int j = 0; j < 4; ++j) {
            const int col = n0 + wn * 64 + j * 16 + r;
#pragma unroll
            for (int t = 0; t < 4; ++t) {
                const size_t off = (size_t)(row + t) * ldc + col;
                const float v = acc[i][j][t];
                if (OUTMODE == 2)      ((float*)C)[off] += v;
                else if (OUTMODE == 1) ((ushort_t*)C)[off] = f2bf(v);
                else                   ((float*)C)[off] = v;
            }
        }
    }
}

// ---------------- RMSNorm: fp32 in -> bf16 out, one wave per row -----------
__global__ __launch_bounds__(256)
void rmsnorm_kernel(const float* __restrict__ x, const float* __restrict__ g,
                    ushort_t* __restrict__ out)
{
    const int w = threadIdx.x >> 6, lane = threadIdx.x & 63;
    const int row = blockIdx.x * 4 + w;
    const float* xr = x + (size_t)row * DIMC;
    float4 a = *(const float4*)(xr + lane * 4);
    float4 b = *(const float4*)(xr + 256 + lane * 4);
    float4 c = *(const float4*)(xr + 512 + lane * 4);
    float ss = a.x*a.x + a.y*a.y + a.z*a.z + a.w*a.w
             + b.x*b.x + b.y*b.y + b.z*b.z + b.w*b.w
             + c.x*c.x + c.y*c.y + c.z*c.z + c.w*c.w;
#pragma unroll
    for (int off = 32; off > 0; off >>= 1) ss += __shfl_xor(ss, off, 64);
    const float inv = rsqrtf(ss * (1.0f / DIMC) + 1e-6f);
    float4 ga = *(const float4*)(g + lane * 4);
    float4 gb = *(const float4*)(g + 256 + lane * 4);
    float4 gc = *(const float4*)(g + 512 + lane * 4);
    ushort_t* orow = out + (size_t)row * DIMC;
    *(ushort4*)(orow + lane * 4)       = make_ushort4(f2bf(a.x*inv*ga.x), f2bf(a.y*inv*ga.y), f2bf(a.z*inv*ga.z), f2bf(a.w*inv*ga.w));
    *(ushort4*)(orow + 256 + lane * 4) = make_ushort4(f2bf(b.x*inv*gb.x), f2bf(b.y*inv*gb.y), f2bf(b.z*inv*gb.z), f2bf(b.w*inv*gb.w));
    *(ushort4*)(orow + 512 + lane * 4) = make_ushort4(f2bf(c.x*inv*gc.x), f2bf(c.y*inv*gc.y), f2bf(c.z*inv*gc.z), f2bf(c.w*inv*gc.w));
}

// ---------------- RoPE in-place on bf16 [S,12,64] --------------------------
__global__ __launch_bounds__(256)
void rope_kernel(ushort_t* __restrict__ x)
{
    const int idx = blockIdx.x * 256 + threadIdx.x;   // SEQL*NHEAD*32
    const int j = idx & 31;
    const int h = (idx >> 5) % NHEAD;
    const int s = idx / (32 * NHEAD);
    const float freq = expf(-0.28782313662425574f * (float)j);
    const float ang = (float)s * freq;
    const float sn = sinf(ang), cs = cosf(ang);
    ushort_t* p = x + (size_t)s * DIMC + h * HDIM + 2 * j;
    const float a = bf2f(p[0]), b = bf2f(p[1]);
    p[0] = f2bf(a * cs - b * sn);
    p[1] = f2bf(a * sn + b * cs);
}

// ---------------- MFMA flash attention, LDS-staged K/V, KVBLK=64 -----------
// Block = 4 waves = 64 q rows (wave w -> rows qb0+16w..+15). Per 64-key chunk:
// cooperative gload_lds staging of K[64x64] and V^T[64x64] tiles (double-
// buffered, XOR-swizzled via pre-swizzled global source, rule "both sides"),
// 8 QK MFMA + 1 softmax round + 8 PV MFMA per wave. Uniform loop: all waves
// run nit=bx+1 chunks; only the last chunk is causal-masked. Longest blocks
// launch first (bx = 31 - blockIdx.x).
__global__ __launch_bounds__(256)
void attn_mfma_kernel(const ushort_t* __restrict__ Q, const ushort_t* __restrict__ K,
                      const ushort_t* __restrict__ VT, ushort_t* __restrict__ O)
{
    __shared__ __align__(16) ushort_t Ks[2][64 * 64];   // [key][d], swizzled rows
    __shared__ __align__(16) ushort_t Vs[2][64 * 64];   // [d][key], swizzled rows

    const int tid = threadIdx.x;
    const int w = tid >> 6, lane = tid & 63;
    const int r = lane & 15, quad = lane >> 4;
    const int hb = blockIdx.y * HDIM;
    const int bx = 31 - (int)blockIdx.x;      // longest-first dispatch
    const int qb0 = bx * 64;
    const int qb = qb0 + w * 16;              // wave q start
    const int nit = bx + 1;                   // 64-key chunks

    // staging map: thread t owns 16B chunks t and t+256 of each 8KB tile.
    // LDS chunk c: row=c>>3, slot=c&7; holds global cols ((slot^(row&7))*8)..+7
    const int c_row = tid >> 3;                               // 0..31 (+32 for 2nd)
    const int c_col = ((tid & 7) ^ (c_row & 7)) << 3;         // element offset, same for both rows (row&7 preserved under +32)
    const int swz = (r & 7) << 4;                             // read-side byte XOR

    // Q fragments (B operand): B[n=r][k=quad*8+j] = Q[qb+r][hb+f*32+quad*8+j] * 1/8
    Frag bq[2];
    {
        const ushort_t* qp = Q + (size_t)(qb + r) * DIMC + hb + quad * 8;
#pragma unroll
        for (int fi = 0; fi < 2; ++fi) {
            Frag t; t.s8 = *(const short8*)(qp + fi * 32);
#pragma unroll
            for (int e = 0; e < 8; ++e) t.us[e] = f2bf(bf2f(t.us[e]) * 0.125f);
            bq[fi] = t;
        }
    }

    floatx4 o[4];
#pragma unroll
    for (int dg = 0; dg < 4; ++dg) o[dg] = (floatx4){0.f, 0.f, 0.f, 0.f};
    float m = -INFINITY, l = 0.f;

    auto stage = [&](int buf, int kc) {
        const ushort_t* kg = K + (size_t)(kc + c_row) * DIMC + hb + c_col;
        GLOAD_LDS16(kg,                        &Ks[buf][(size_t)tid * 8]);
        GLOAD_LDS16(kg + (size_t)32 * DIMC,    &Ks[buf][(size_t)(tid + 256) * 8]);
        const ushort_t* vg = VT + (size_t)(hb + c_row) * SEQL + kc + c_col;
        GLOAD_LDS16(vg,                        &Vs[buf][(size_t)tid * 8]);
        GLOAD_LDS16(vg + (size_t)32 * SEQL,    &Vs[buf][(size_t)(tid + 256) * 8]);
    };

    stage(0, 0);
    __syncthreads();   // chunk 0 resident

    for (int it = 0; it < nit; ++it) {
        const int buf = it & 1;
        const int kc = it * 64;
        if (it + 1 < nit) stage(buf ^ 1, kc + 64);   // issue early, drains at end barrier

        const char* ksb = (const char*)Ks[buf];
        const char* vsb = (const char*)Vs[buf];

        // QK^T: st[s][tt] = score(key kc+s*16+quad*4+tt, q=qb+r)
        floatx4 st[4];
#pragma unroll
        for (int s = 0; s < 4; ++s) {
            st[s] = (floatx4){0.f, 0.f, 0.f, 0.f};
#pragma unroll
            for (int f = 0; f < 2; ++f) {
                const int lb = (s * 16 + r) * 128 + ((f * 64 + quad * 16) ^ swz);
                const short8 a = *(const short8*)(ksb + lb);
                st[s] = __builtin_amdgcn_mfma_f32_16x16x32_bf16(a, bq[f].s8, st[s], 0, 0, 0);
            }
        }

        if (it == nit - 1) {   // causal mask, only final chunk
            const int q = qb + r;
#pragma unroll
            for (int s = 0; s < 4; ++s)
#pragma unroll
                for (int tt = 0; tt < 4; ++tt)
                    if (kc + s * 16 + quad * 4 + tt > q) st[s][tt] = -INFINITY;
        }

        // online softmax (one round per 64 keys)
        float vm = -INFINITY;
#pragma unroll
        for (int s = 0; s < 4; ++s)
            vm = fmaxf(vm, fmaxf(fmaxf(st[s][0], st[s][1]), fmaxf(st[s][2], st[s][3])));
        vm = fmaxf(vm, __shfl_xor(vm, 16, 64));
        vm = fmaxf(vm, __shfl_xor(vm, 32, 64));
        const float mnew = fmaxf(m, vm);
        const float alpha = __expf(m - mnew);
        float p[4][4];
        float ps = 0.f;
#pragma unroll
        for (int s = 0; s < 4; ++s)
#pragma unroll
            for (int tt = 0; tt < 4; ++tt) {
                p[s][tt] = __expf(st[s][tt] - mnew);
                ps += p[s][tt];
            }
        ps += __shfl_xor(ps, 16, 64);
        ps += __shfl_xor(ps, 32, 64);
        l = l * alpha + ps;
        m = mnew;

        // P fragments (B operand), key-half kh covers keys kc+kh*32..+31
        Frag ap0, ap1;
        ap0.u[0] = (uint32)f2bf(p[0][0]) | ((uint32)f2bf(p[0][1]) << 16);
        ap0.u[1] = (uint32)f2bf(p[0][2]) | ((uint32)f2bf(p[0][3]) << 16);
        ap0.u[2] = (uint32)f2bf(p[1][0]) | ((uint32)f2bf(p[1][1]) << 16);
        ap0.u[3] = (uint32)f2bf(p[1][2]) | ((uint32)f2bf(p[1][3]) << 16);
        ap1.u[0] = (uint32)f2bf(p[2][0]) | ((uint32)f2bf(p[2][1]) << 16);
        ap1.u[1] = (uint32)f2bf(p[2][2]) | ((uint32)f2bf(p[2][3]) << 16);
        ap1.u[2] = (uint32)f2bf(p[3][0]) | ((uint32)f2bf(p[3][1]) << 16);
        ap1.u[3] = (uint32)f2bf(p[3][2]) | ((uint32)f2bf(p[3][3]) << 16);

        // PV: o[dg] = mfma(V^T frag, P frag, o[dg]*alpha), V from LDS
#pragma unroll
        for (int dg = 0; dg < 4; ++dg) {
            const int rowb = (dg * 16 + r) * 128;
            Frag av0, av1;
            *(uint2*)&av0.u[0] = *(const uint2*)(vsb + rowb + ((quad * 8) ^ swz));
            *(uint2*)&av0.u[2] = *(const uint2*)(vsb + rowb + ((32 + quad * 8) ^ swz));
            *(uint2*)&av1.u[0] = *(const uint2*)(vsb + rowb + ((64 + quad * 8) ^ swz));
            *(uint2*)&av1.u[2] = *(const uint2*)(vsb + rowb + ((96 + quad * 8) ^ swz));
            o[dg] *= alpha;
            o[dg] = __builtin_amdgcn_mfma_f32_16x16x32_bf16(av0.s8, ap0.s8, o[dg], 0, 0, 0);
            o[dg] = __builtin_amdgcn_mfma_f32_16x16x32_bf16(av1.s8, ap1.s8, o[dg], 0, 0, 0);
        }

        __syncthreads();   // drains next-chunk staging; all waves done with buf
    }

    // write O: lane holds O^T[d=dg*16+quad*4+t][q=qb+r]
    const float inv = 1.0f / l;
    ushort_t* op = O + (size_t)(qb + r) * DIMC + hb + quad * 4;
#pragma unroll
    for (int dg = 0; dg < 4; ++dg) {
        uint2 pkd;
        pkd.x = (uint32)f2bf(o[dg][0] * inv) | ((uint32)f2bf(o[dg][1] * inv) << 16);
        pkd.y = (uint32)f2bf(o[dg][2] * inv) | ((uint32)f2bf(o[dg][3] * inv) << 16);
        *(uint2*)(op + dg * 16) = pkd;
    }
}

// ---------------- SiLU(y1) * y3 -> bf16, fused Y13 layout [2048][4096] -----
// cols 0..2047 = y1, cols 2048..4095 = y3 (padded cols give silu(0)*0 = 0)
__global__ __launch_bounds__(256)
void silu_mul_kernel(const float* __restrict__ y13, ushort_t* __restrict__ hs)
{
    const int idx = blockIdx.x * 256 + threadIdx.x;   // 2048*512
    const int s = idx >> 9;
    const int c = (idx & 511) * 4;
    const float* row = y13 + (size_t)s * 4096;
    float4 a = *(const float4*)(row + c);
    float4 b = *(const float4*)(row + 2048 + c);
    float4 r;
    r.x = a.x / (1.f + __expf(-a.x)) * b.x;
    r.y = a.y / (1.f + __expf(-a.y)) * b.y;
    r.z = a.z / (1.f + __expf(-a.z)) * b.z;
    r.w = a.w / (1.f + __expf(-a.w)) * b.w;
    *(ushort4*)(hs + (size_t)s * HIDP + c) = make_ushort4(f2bf(r.x), f2bf(r.y), f2bf(r.z), f2bf(r.w));
}

// ---------------- Embedding gather (fp32) ----------------------------------
__global__ __launch_bounds__(256)
void embed_kernel(const int* __restrict__ tok, const float* __restrict__ emb,
                  float* __restrict__ h)
{
    const int idx = blockIdx.x * 256 + threadIdx.x;    // SEQL*192
    const int s = idx / 192, c = (idx % 192) * 4;
    const int t = tok[s];
    *(float4*)(h + (size_t)s * DIMC + c) = *(const float4*)(emb + (size_t)t * DIMC + c);
}

// ---------------- Per-layer weight conversion fp32 -> bf16 (with padding) --
__global__ __launch_bounds__(256)
void conv_layer_kernel(const float* __restrict__ wq, const float* __restrict__ wk,
                       const float* __restrict__ wv, const float* __restrict__ wo,
                       const float* __restrict__ w1, const float* __restrict__ w2,
                       const float* __restrict__ w3,
                       ushort_t* __restrict__ wqb, ushort_t* __restrict__ wkb,
                       ushort_t* __restrict__ wvb, ushort_t* __restrict__ wob,
                       ushort_t* __restrict__ w1p, ushort_t* __restrict__ w3p,
                       ushort_t* __restrict__ w2p)
{
    int idx = blockIdx.x * 256 + threadIdx.x;
    if (idx < 4 * QSZ) {
        const int m = idx / QSZ, i = idx - m * QSZ;
        const float* s = (m == 0) ? wq : (m == 1) ? wk : (m == 2) ? wv : wo;
        ushort_t*   d = (m == 0) ? wqb : (m == 1) ? wkb : (m == 2) ? wvb : wob;
        d[i] = f2bf(s[i]);
        return;
    }
    idx -= 4 * QSZ;
    if (idx < PSZ) {   // w1 padded: [2048][768], rows >= 2042 zero
        const int n = idx / DIMC, kk = idx - n * DIMC;
        w1p[idx] = (n < HIDV) ? f2bf(w1[(size_t)n * DIMC + kk]) : (ushort_t)0;
        return;
    }
    idx -= PSZ;
    if (idx < PSZ) {
        const int n = idx / DIMC, kk = idx - n * DIMC;
        w3p[idx] = (n < HIDV) ? f2bf(w3[(size_t)n * DIMC + kk]) : (ushort_t)0;
        return;
    }
    idx -= PSZ;
    if (idx < PSZ) {   // w2 padded: [768][2048], cols >= 2042 zero
        const int n = idx >> 11, kk = idx & 2047;
        w2p[idx] = (kk < HIDV) ? f2bf(w2[(size_t)n * HIDV + kk]) : (ushort_t)0;
        return;
    }
}

// ---------------- out_w conversion fp32 -> bf16 ----------------------------
__global__ __launch_bounds__(256)
void conv_outw_kernel(const float* __restrict__ src, ushort_t* __restrict__ dst)
{
    const size_t idx = (size_t)(blockIdx.x * 256 + threadIdx.x);
    float4 a = *(const float4*)(src + idx * 4);
    *(ushort4*)(dst + idx * 4) = make_ushort4(f2bf(a.x), f2bf(a.y), f2bf(a.z), f2bf(a.w));
}

extern "C" void kernel_launch(void* const* d_in, const int* in_sizes, int n_in,
                              void* d_out, int out_size, void* d_ws, size_t ws_size,
                              hipStream_t stream)
{
    const int*   tok  = (const int*)d_in[0];
    const float* emb  = (const float*)d_in[1];
    const float* wq   = (const float*)d_in[2];
    const float* wk   = (const float*)d_in[3];
    const float* wv   = (const float*)d_in[4];
    const float* wo   = (const float*)d_in[5];
    const float* w1   = (const float*)d_in[6];
    const float* w2   = (const float*)d_in[7];
    const float* w3   = (const float*)d_in[8];
    const float* anw  = (const float*)d_in[9];
    const float* fnw  = (const float*)d_in[10];
    const float* nw   = (const float*)d_in[11];
    const float* outw = (const float*)d_in[12];
    float* out = (float*)d_out;
    (void)in_sizes; (void)n_in; (void)out_size; (void)ws_size;

    char* p = (char*)d_ws;
    auto alloc = [&](size_t bytes) { char* r = p; p += (bytes + 255) & ~(size_t)255; return r; };
    float*    H   = (float*)   alloc((size_t)SEQL * DIMC * 4);
    ushort_t* XN  = (ushort_t*)alloc((size_t)SEQL * DIMC * 2);
    ushort_t* YN  = (ushort_t*)alloc((size_t)SEQL * DIMC * 2);
    ushort_t* WQB = (ushort_t*)alloc((size_t)QSZ * 2);
    ushort_t* WKB = (ushort_t*)alloc((size_t)QSZ * 2);
    ushort_t* WVB = (ushort_t*)alloc((size_t)QSZ * 2);
    ushort_t* WOB = (ushort_t*)alloc((size_t)QSZ * 2);
    // W1P and W3P MUST stay adjacent: fused FFN-up GEMM treats them as one
    // [4096][768] B matrix (PSZ*2 bytes is 256-aligned so no gap).
    ushort_t* W1P = (ushort_t*)alloc((size_t)PSZ * 2);
    ushort_t* W3P = (ushort_t*)alloc((size_t)PSZ * 2);
    ushort_t* W2P = (ushort_t*)alloc((size_t)PSZ * 2);
    // region below is reused late as bf16 out_w (52 MB >= 49.15 MB)
    ushort_t* QB  = (ushort_t*)alloc((size_t)SEQL * DIMC * 2);
    ushort_t* KB  = (ushort_t*)alloc((size_t)SEQL * DIMC * 2);
    ushort_t* VTG = (ushort_t*)alloc((size_t)SEQL * DIMC * 2);  // V^T [DIMC][SEQL]
    ushort_t* AO  = (ushort_t*)alloc((size_t)SEQL * DIMC * 2);
    float*    Y13 = (float*)   alloc((size_t)SEQL * 4096 * 4);  // [2048][4096] y1|y3
    ushort_t* HS  = (ushort_t*)alloc((size_t)SEQL * HIDP * 2);
    ushort_t* OUTWB = QB;  // aliased, used only after last layer

    embed_kernel<<<1536, 256, 0, stream>>>(tok, emb, H);

    for (int l = 0; l < 4; ++l) {
        conv_layer_kernel<<<27648, 256, 0, stream>>>(
            wq + (size_t)l * QSZ, wk + (size_t)l * QSZ, wv + (size_t)l * QSZ, wo + (size_t)l * QSZ,
            w1 + (size_t)l * W2SRC, w2 + (size_t)l * W2SRC, w3 + (size_t)l * W2SRC,
            WQB, WKB, WVB, WOB, W1P, W3P, W2P);

        rmsnorm_kernel<<<512, 256, 0, stream>>>(H, anw + (size_t)l * DIMC, XN);

        // Q,K projections (bf16 out): M=2048 N=768 K=768, 64x64 tiles
        gemm_kernel<2,2,2,2,1><<<dim3(32,12), 256, 0, stream>>>(XN, DIMC, WQB, DIMC, QB, DIMC, DIMC);
        gemm_kernel<2,2,2,2,1><<<dim3(32,12), 256, 0, stream>>>(XN, DIMC, WKB, DIMC, KB, DIMC, DIMC);
        // V^T projection (swapped operands): C[d][s] = sum_k Wv[d][k] X[s][k]
        gemm_kernel<2,2,2,2,1><<<dim3(12,32), 256, 0, stream>>>(WVB, DIMC, XN, DIMC, VTG, SEQL, DIMC);

        rope_kernel<<<3072, 256, 0, stream>>>(QB);
        rope_kernel<<<3072, 256, 0, stream>>>(KB);

        attn_mfma_kernel<<<dim3(32, NHEAD), 256, 0, stream>>>(QB, KB, VTG, AO);

        // o @ wo^T, accumulate into H (residual)
        gemm_kernel<2,2,2,2,2><<<dim3(32,12), 256, 0, stream>>>(AO, DIMC, WOB, DIMC, H, DIMC, DIMC);

        rmsnorm_kernel<<<512, 256, 0, stream>>>(H, fnw + (size_t)l * DIMC, YN);

        // FFN up, FUSED w1|w3: M=2048 N=4096 K=768, LDS-staged 128x128 tiles
        gemm_lds_kernel<0><<<dim3(16,32), 256, 0, stream>>>(YN, DIMC, W1P, DIMC, Y13, 4096, DIMC);

        silu_mul_kernel<<<4096, 256, 0, stream>>>(Y13, HS);

        // FFN down: M=2048 N=768 K=2048(pad), accumulate into H
        gemm_kernel<2,2,2,2,2><<<dim3(32,12), 256, 0, stream>>>(HS, HIDP, W2P, HIDP, H, DIMC, HIDP);
    }

    rmsnorm_kernel<<<512, 256, 0, stream>>>(H, nw, XN);
    conv_outw_kernel<<<24000, 256, 0, stream>>>(outw, OUTWB);
    // logits: M=2048 N=32000 K=768, LDS-staged 128x128 tiles, f32 out
    gemm_lds_kernel<0><<<dim3(16,250), 256, 0, stream>>>(XN, DIMC, OUTWB, DIMC, out, NVOCAB, DIMC);
}

// Round 4
// 1345.922 us; speedup vs baseline: 1.7892x; 1.2134x over previous
//
#include <hip/hip_runtime.h>
#include <math.h>

typedef unsigned int uint32;
typedef unsigned short ushort_t;

typedef __attribute__((ext_vector_type(8))) short short8;
typedef __attribute__((ext_vector_type(4))) float floatx4;

#define SEQL 2048
#define DIMC 768
#define NHEAD 12
#define HDIM 64
#define HIDV 2042
#define HIDP 2048
#define NVOCAB 32000
#define QKS 1536             // fused Q|K row stride
#define QSZ (DIMC*DIMC)      // 589824
#define PSZ (HIDP*DIMC)      // 1572864
#define W2SRC (DIMC*HIDV)    // 1568256

__device__ __forceinline__ ushort_t f2bf(float f) {
    uint32 u = __float_as_uint(f);
    u += 0x7FFFu + ((u >> 16) & 1u);   // round-to-nearest-even
    return (ushort_t)(u >> 16);
}
__device__ __forceinline__ float bf2f(ushort_t h) {
    return __uint_as_float(((uint32)h) << 16);
}

union Frag { short8 s8; uint32 u[4]; ushort_t us[8]; };

// async global->LDS 16B copy (dest must be linear in lane order within wave)
#define GLOAD_LDS16(g, l) \
    __builtin_amdgcn_global_load_lds((const __attribute__((address_space(1))) void*)(g), \
                                     (__attribute__((address_space(3))) void*)(l), 16, 0, 0)

// ---------------- LDS-staged GEMM, double-buffered 2-phase, XCD-swizzled ---
// C[M,N] (=|+=) A[M,K] * B[N,K]^T, bf16 in. BM,BN in {64,128}; 4 waves (2x2),
// wave tile (BM/2)x(BN/2). Staging: thread t owns 16B chunk t (and t+256 when
// the tile has 128 rows) -> per-wave LDS dest is base + lane*16 (linear, as
// global_load_lds requires). stage(t+1) issues before compute(t); the single
// __syncthreads per iter drains vmcnt (prefetch flight overlaps MFMA).
// Block swizzle: bijective XCD chunking (requires gridDim.x*gridDim.y % 8 == 0).
// OUTMODE: 0 = store f32, 1 = store bf16, 2 = accumulate into f32 (residual)
template<int BM, int BN, int OUTMODE>
__global__ __launch_bounds__(256)
void gemm_lds_kernel(const ushort_t* __restrict__ A, int lda,
                     const ushort_t* __restrict__ B, int ldb,
                     void* __restrict__ C, int ldc, int K)
{
    constexpr int WTM = BM / 32;
    constexpr int WTN = BN / 32;
    __shared__ __align__(16) ushort_t As[2][BM * 32];
    __shared__ __align__(16) ushort_t Bs[2][BN * 32];

    const int tid = threadIdx.x;
    // bijective XCD swizzle: lid = xcd*(nwg/8) + pos
    const int nwg  = gridDim.x * gridDim.y;
    const int lid0 = blockIdx.y * gridDim.x + blockIdx.x;
    const int lid  = (lid0 & 7) * (nwg >> 3) + (lid0 >> 3);
    const int bx = lid % gridDim.x;
    const int by = lid / gridDim.x;

    const int wid = tid >> 6, lane = tid & 63;
    const int wm = wid & 1, wn = wid >> 1;
    const int r = lane & 15, quad = lane >> 4;
    const int m0 = bx * BM;
    const int n0 = by * BN;

    floatx4 acc[WTM][WTN];
#pragma unroll
    for (int i = 0; i < WTM; ++i)
#pragma unroll
        for (int j = 0; j < WTN; ++j) acc[i][j] = (floatx4){0.f, 0.f, 0.f, 0.f};

    const int row_a = tid >> 2;          // 0..63
    const int col8  = (tid & 3) * 8;
    const ushort_t* gA = A + (size_t)(m0 + row_a) * lda + col8;
    const ushort_t* gB = B + (size_t)(n0 + row_a) * ldb + col8;

    auto stage = [&](int buf, int k0) {
        GLOAD_LDS16(gA + k0, &As[buf][(size_t)tid * 8]);
        if (BM == 128) GLOAD_LDS16(gA + (size_t)64 * lda + k0, &As[buf][(size_t)(tid + 256) * 8]);
        GLOAD_LDS16(gB + k0, &Bs[buf][(size_t)tid * 8]);
        if (BN == 128) GLOAD_LDS16(gB + (size_t)64 * ldb + k0, &Bs[buf][(size_t)(tid + 256) * 8]);
    };

    stage(0, 0);
    __syncthreads();
    int buf = 0;
    for (int k0 = 0; k0 < K; k0 += 32) {
        if (k0 + 32 < K) stage(buf ^ 1, k0 + 32);   // prefetch overlaps MFMA below
        const ushort_t* pa = &As[buf][(wm * (BM / 2) + r) * 32 + quad * 8];
        const ushort_t* pb = &Bs[buf][(wn * (BN / 2) + r) * 32 + quad * 8];
        short8 af[WTM], bf[WTN];
#pragma unroll
        for (int i = 0; i < WTM; ++i) af[i] = *(const short8*)(pa + i * 16 * 32);
#pragma unroll
        for (int j = 0; j < WTN; ++j) bf[j] = *(const short8*)(pb + j * 16 * 32);
#pragma unroll
        for (int i = 0; i < WTM; ++i)
#pragma unroll
            for (int j = 0; j < WTN; ++j)
                acc[i][j] = __builtin_amdgcn_mfma_f32_16x16x32_bf16(af[i], bf[j], acc[i][j], 0, 0, 0);
        __syncthreads();   // drains prefetch + protects buf for next overwrite
        buf ^= 1;
    }

#pragma unroll
    for (int i = 0; i < WTM; ++i) {
        const int row = m0 + wm * (BM / 2) + i * 16 + quad * 4;
#pragma unroll
        for (int j = 0; j < WTN; ++j) {
            const int col = n0 + wn * (BN / 2) + j * 16 + r;
#pragma unroll
            for (int t = 0; t < 4; ++t) {
                const size_t off = (size_t)(row + t) * ldc + col;
                const float v = acc[i][j][t];
                if (OUTMODE == 2)      ((float*)C)[off] += v;
                else if (OUTMODE == 1) ((ushort_t*)C)[off] = f2bf(v);
                else                   ((float*)C)[off] = v;
            }
        }
    }
}

// ---------------- RMSNorm: fp32 in -> bf16 out, one wave per row -----------
__global__ __launch_bounds__(256)
void rmsnorm_kernel(const float* __restrict__ x, const float* __restrict__ g,
                    ushort_t* __restrict__ out)
{
    const int w = threadIdx.x >> 6, lane = threadIdx.x & 63;
    const int row = blockIdx.x * 4 + w;
    const float* xr = x + (size_t)row * DIMC;
    float4 a = *(const float4*)(xr + lane * 4);
    float4 b = *(const float4*)(xr + 256 + lane * 4);
    float4 c = *(const float4*)(xr + 512 + lane * 4);
    float ss = a.x*a.x + a.y*a.y + a.z*a.z + a.w*a.w
             + b.x*b.x + b.y*b.y + b.z*b.z + b.w*b.w
             + c.x*c.x + c.y*c.y + c.z*c.z + c.w*c.w;
#pragma unroll
    for (int off = 32; off > 0; off >>= 1) ss += __shfl_xor(ss, off, 64);
    const float inv = rsqrtf(ss * (1.0f / DIMC) + 1e-6f);
    float4 ga = *(const float4*)(g + lane * 4);
    float4 gb = *(const float4*)(g + 256 + lane * 4);
    float4 gc = *(const float4*)(g + 512 + lane * 4);
    ushort_t* orow = out + (size_t)row * DIMC;
    *(ushort4*)(orow + lane * 4)       = make_ushort4(f2bf(a.x*inv*ga.x), f2bf(a.y*inv*ga.y), f2bf(a.z*inv*ga.z), f2bf(a.w*inv*ga.w));
    *(ushort4*)(orow + 256 + lane * 4) = make_ushort4(f2bf(b.x*inv*gb.x), f2bf(b.y*inv*gb.y), f2bf(b.z*inv*gb.z), f2bf(b.w*inv*gb.w));
    *(ushort4*)(orow + 512 + lane * 4) = make_ushort4(f2bf(c.x*inv*gc.x), f2bf(c.y*inv*gc.y), f2bf(c.z*inv*gc.z), f2bf(c.w*inv*gc.w));
}

// ---------------- RoPE in-place on fused QK [S][24*64] ---------------------
// heads 0..11 = Q, 12..23 = K; angle depends only on (s, j) so one launch
// rotates both. grid: SEQL*24*32/256 = 6144
__global__ __launch_bounds__(256)
void rope_kernel(ushort_t* __restrict__ x)
{
    const int idx = blockIdx.x * 256 + threadIdx.x;
    const int j = idx & 31;
    const int h = (idx >> 5) % 24;
    const int s = idx / 768;
    const float freq = expf(-0.28782313662425574f * (float)j);
    const float ang = (float)s * freq;
    const float sn = sinf(ang), cs = cosf(ang);
    ushort_t* p = x + (size_t)s * QKS + h * HDIM + 2 * j;
    const float a = bf2f(p[0]), b = bf2f(p[1]);
    p[0] = f2bf(a * cs - b * sn);
    p[1] = f2bf(a * sn + b * cs);
}

// ---------------- MFMA flash attention, LDS-staged K/V, KVBLK=64 -----------
// Q,K live in the fused QK buffer (row stride qks); V^T stride SEQL.
__global__ __launch_bounds__(256)
void attn_mfma_kernel(const ushort_t* __restrict__ Q, const ushort_t* __restrict__ K,
                      const ushort_t* __restrict__ VT, ushort_t* __restrict__ O,
                      int qks)
{
    __shared__ __align__(16) ushort_t Ks[2][64 * 64];   // [key][d], swizzled rows
    __shared__ __align__(16) ushort_t Vs[2][64 * 64];   // [d][key], swizzled rows

    const int tid = threadIdx.x;
    const int w = tid >> 6, lane = tid & 63;
    const int r = lane & 15, quad = lane >> 4;
    const int hb = blockIdx.y * HDIM;
    const int bx = 31 - (int)blockIdx.x;      // longest-first dispatch
    const int qb = bx * 64 + w * 16;          // wave q start
    const int nit = bx + 1;                   // 64-key chunks

    const int c_row = tid >> 3;
    const int c_col = ((tid & 7) ^ (c_row & 7)) << 3;
    const int swz = (r & 7) << 4;             // read-side byte XOR

    Frag bq[2];
    {
        const ushort_t* qp = Q + (size_t)(qb + r) * qks + hb + quad * 8;
#pragma unroll
        for (int fi = 0; fi < 2; ++fi) {
            Frag t; t.s8 = *(const short8*)(qp + fi * 32);
#pragma unroll
            for (int e = 0; e < 8; ++e) t.us[e] = f2bf(bf2f(t.us[e]) * 0.125f);
            bq[fi] = t;
        }
    }

    floatx4 o[4];
#pragma unroll
    for (int dg = 0; dg < 4; ++dg) o[dg] = (floatx4){0.f, 0.f, 0.f, 0.f};
    float m = -INFINITY, l = 0.f;

    auto stage = [&](int buf, int kc) {
        const ushort_t* kg = K + (size_t)(kc + c_row) * qks + hb + c_col;
        GLOAD_LDS16(kg,                      &Ks[buf][(size_t)tid * 8]);
        GLOAD_LDS16(kg + (size_t)32 * qks,   &Ks[buf][(size_t)(tid + 256) * 8]);
        const ushort_t* vg = VT + (size_t)(hb + c_row) * SEQL + kc + c_col;
        GLOAD_LDS16(vg,                      &Vs[buf][(size_t)tid * 8]);
        GLOAD_LDS16(vg + (size_t)32 * SEQL,  &Vs[buf][(size_t)(tid + 256) * 8]);
    };

    stage(0, 0);
    __syncthreads();

    for (int it = 0; it < nit; ++it) {
        const int buf = it & 1;
        const int kc = it * 64;
        if (it + 1 < nit) stage(buf ^ 1, kc + 64);

        const char* ksb = (const char*)Ks[buf];
        const char* vsb = (const char*)Vs[buf];

        floatx4 st[4];
#pragma unroll
        for (int s = 0; s < 4; ++s) {
            st[s] = (floatx4){0.f, 0.f, 0.f, 0.f};
#pragma unroll
            for (int f = 0; f < 2; ++f) {
                const int lb = (s * 16 + r) * 128 + ((f * 64 + quad * 16) ^ swz);
                const short8 a = *(const short8*)(ksb + lb);
                st[s] = __builtin_amdgcn_mfma_f32_16x16x32_bf16(a, bq[f].s8, st[s], 0, 0, 0);
            }
        }

        if (it == nit - 1) {
            const int q = qb + r;
#pragma unroll
            for (int s = 0; s < 4; ++s)
#pragma unroll
                for (int tt = 0; tt < 4; ++tt)
                    if (kc + s * 16 + quad * 4 + tt > q) st[s][tt] = -INFINITY;
        }

        float vm = -INFINITY;
#pragma unroll
        for (int s = 0; s < 4; ++s)
            vm = fmaxf(vm, fmaxf(fmaxf(st[s][0], st[s][1]), fmaxf(st[s][2], st[s][3])));
        vm = fmaxf(vm, __shfl_xor(vm, 16, 64));
        vm = fmaxf(vm, __shfl_xor(vm, 32, 64));
        const float mnew = fmaxf(m, vm);
        const float alpha = __expf(m - mnew);
        float p[4][4];
        float ps = 0.f;
#pragma unroll
        for (int s = 0; s < 4; ++s)
#pragma unroll
            for (int tt = 0; tt < 4; ++tt) {
                p[s][tt] = __expf(st[s][tt] - mnew);
                ps += p[s][tt];
            }
        ps += __shfl_xor(ps, 16, 64);
        ps += __shfl_xor(ps, 32, 64);
        l = l * alpha + ps;
        m = mnew;

        Frag ap0, ap1;
        ap0.u[0] = (uint32)f2bf(p[0][0]) | ((uint32)f2bf(p[0][1]) << 16);
        ap0.u[1] = (uint32)f2bf(p[0][2]) | ((uint32)f2bf(p[0][3]) << 16);
        ap0.u[2] = (uint32)f2bf(p[1][0]) | ((uint32)f2bf(p[1][1]) << 16);
        ap0.u[3] = (uint32)f2bf(p[1][2]) | ((uint32)f2bf(p[1][3]) << 16);
        ap1.u[0] = (uint32)f2bf(p[2][0]) | ((uint32)f2bf(p[2][1]) << 16);
        ap1.u[1] = (uint32)f2bf(p[2][2]) | ((uint32)f2bf(p[2][3]) << 16);
        ap1.u[2] = (uint32)f2bf(p[3][0]) | ((uint32)f2bf(p[3][1]) << 16);
        ap1.u[3] = (uint32)f2bf(p[3][2]) | ((uint32)f2bf(p[3][3]) << 16);

#pragma unroll
        for (int dg = 0; dg < 4; ++dg) {
            const int rowb = (dg * 16 + r) * 128;
            Frag av0, av1;
            *(uint2*)&av0.u[0] = *(const uint2*)(vsb + rowb + ((quad * 8) ^ swz));
            *(uint2*)&av0.u[2] = *(const uint2*)(vsb + rowb + ((32 + quad * 8) ^ swz));
            *(uint2*)&av1.u[0] = *(const uint2*)(vsb + rowb + ((64 + quad * 8) ^ swz));
            *(uint2*)&av1.u[2] = *(const uint2*)(vsb + rowb + ((96 + quad * 8) ^ swz));
            o[dg] *= alpha;
            o[dg] = __builtin_amdgcn_mfma_f32_16x16x32_bf16(av0.s8, ap0.s8, o[dg], 0, 0, 0);
            o[dg] = __builtin_amdgcn_mfma_f32_16x16x32_bf16(av1.s8, ap1.s8, o[dg], 0, 0, 0);
        }

        __syncthreads();
    }

    const float inv = 1.0f / l;
    ushort_t* op = O + (size_t)(qb + r) * DIMC + hb + quad * 4;
#pragma unroll
    for (int dg = 0; dg < 4; ++dg) {
        uint2 pkd;
        pkd.x = (uint32)f2bf(o[dg][0] * inv) | ((uint32)f2bf(o[dg][1] * inv) << 16);
        pkd.y = (uint32)f2bf(o[dg][2] * inv) | ((uint32)f2bf(o[dg][3] * inv) << 16);
        *(uint2*)(op + dg * 16) = pkd;
    }
}

// ---------------- SiLU(y1) * y3 -> bf16, fused Y13 layout [2048][4096] -----
__global__ __launch_bounds__(256)
void silu_mul_kernel(const float* __restrict__ y13, ushort_t* __restrict__ hs)
{
    const int idx = blockIdx.x * 256 + threadIdx.x;   // 2048*512
    const int s = idx >> 9;
    const int c = (idx & 511) * 4;
    const float* row = y13 + (size_t)s * 4096;
    float4 a = *(const float4*)(row + c);
    float4 b = *(const float4*)(row + 2048 + c);
    float4 r;
    r.x = a.x / (1.f + __expf(-a.x)) * b.x;
    r.y = a.y / (1.f + __expf(-a.y)) * b.y;
    r.z = a.z / (1.f + __expf(-a.z)) * b.z;
    r.w = a.w / (1.f + __expf(-a.w)) * b.w;
    *(ushort4*)(hs + (size_t)s * HIDP + c) = make_ushort4(f2bf(r.x), f2bf(r.y), f2bf(r.z), f2bf(r.w));
}

// ---------------- Embedding gather (fp32) ----------------------------------
__global__ __launch_bounds__(256)
void embed_kernel(const int* __restrict__ tok, const float* __restrict__ emb,
                  float* __restrict__ h)
{
    const int idx = blockIdx.x * 256 + threadIdx.x;    // SEQL*192
    const int s = idx / 192, c = (idx % 192) * 4;
    const int t = tok[s];
    *(float4*)(h + (size_t)s * DIMC + c) = *(const float4*)(emb + (size_t)t * DIMC + c);
}

// ---------------- Per-layer weight conversion fp32 -> bf16 (with padding) --
__global__ __launch_bounds__(256)
void conv_layer_kernel(const float* __restrict__ wq, const float* __restrict__ wk,
                       const float* __restrict__ wv, const float* __restrict__ wo,
                       const float* __restrict__ w1, const float* __restrict__ w2,
                       const float* __restrict__ w3,
                       ushort_t* __restrict__ wqb, ushort_t* __restrict__ wkb,
                       ushort_t* __restrict__ wvb, ushort_t* __restrict__ wob,
                       ushort_t* __restrict__ w1p, ushort_t* __restrict__ w3p,
                       ushort_t* __restrict__ w2p)
{
    int idx = blockIdx.x * 256 + threadIdx.x;
    if (idx < 4 * QSZ) {
        const int m = idx / QSZ, i = idx - m * QSZ;
        const float* s = (m == 0) ? wq : (m == 1) ? wk : (m == 2) ? wv : wo;
        ushort_t*   d = (m == 0) ? wqb : (m == 1) ? wkb : (m == 2) ? wvb : wob;
        d[i] = f2bf(s[i]);
        return;
    }
    idx -= 4 * QSZ;
    if (idx < PSZ) {   // w1 padded: [2048][768], rows >= 2042 zero
        const int n = idx / DIMC, kk = idx - n * DIMC;
        w1p[idx] = (n < HIDV) ? f2bf(w1[(size_t)n * DIMC + kk]) : (ushort_t)0;
        return;
    }
    idx -= PSZ;
    if (idx < PSZ) {
        const int n = idx / DIMC, kk = idx - n * DIMC;
        w3p[idx] = (n < HIDV) ? f2bf(w3[(size_t)n * DIMC + kk]) : (ushort_t)0;
        return;
    }
    idx -= PSZ;
    if (idx < PSZ) {   // w2 padded: [768][2048], cols >= 2042 zero
        const int n = idx >> 11, kk = idx & 2047;
        w2p[idx] = (kk < HIDV) ? f2bf(w2[(size_t)n * HIDV + kk]) : (ushort_t)0;
        return;
    }
}

// ---------------- out_w conversion fp32 -> bf16 ----------------------------
__global__ __launch_bounds__(256)
void conv_outw_kernel(const float* __restrict__ src, ushort_t* __restrict__ dst)
{
    const size_t idx = (size_t)(blockIdx.x * 256 + threadIdx.x);
    float4 a = *(const float4*)(src + idx * 4);
    *(ushort4*)(dst + idx * 4) = make_ushort4(f2bf(a.x), f2bf(a.y), f2bf(a.z), f2bf(a.w));
}

extern "C" void kernel_launch(void* const* d_in, const int* in_sizes, int n_in,
                              void* d_out, int out_size, void* d_ws, size_t ws_size,
                              hipStream_t stream)
{
    const int*   tok  = (const int*)d_in[0];
    const float* emb  = (const float*)d_in[1];
    const float* wq   = (const float*)d_in[2];
    const float* wk   = (const float*)d_in[3];
    const float* wv   = (const float*)d_in[4];
    const float* wo   = (const float*)d_in[5];
    const float* w1   = (const float*)d_in[6];
    const float* w2   = (const float*)d_in[7];
    const float* w3   = (const float*)d_in[8];
    const float* anw  = (const float*)d_in[9];
    const float* fnw  = (const float*)d_in[10];
    const float* nw   = (const float*)d_in[11];
    const float* outw = (const float*)d_in[12];
    float* out = (float*)d_out;
    (void)in_sizes; (void)n_in; (void)out_size; (void)ws_size;

    char* p = (char*)d_ws;
    auto alloc = [&](size_t bytes) { char* r = p; p += (bytes + 255) & ~(size_t)255; return r; };
    float*    H   = (float*)   alloc((size_t)SEQL * DIMC * 4);
    ushort_t* XN  = (ushort_t*)alloc((size_t)SEQL * DIMC * 2);
    ushort_t* YN  = (ushort_t*)alloc((size_t)SEQL * DIMC * 2);
    // WQB and WKB MUST stay adjacent: fused QK GEMM treats them as one
    // [1536][768] B matrix (QSZ*2 bytes is 256-aligned so no gap).
    ushort_t* WQB = (ushort_t*)alloc((size_t)QSZ * 2);
    ushort_t* WKB = (ushort_t*)alloc((size_t)QSZ * 2);
    ushort_t* WVB = (ushort_t*)alloc((size_t)QSZ * 2);
    ushort_t* WOB = (ushort_t*)alloc((size_t)QSZ * 2);
    // W1P and W3P MUST stay adjacent (fused FFN-up GEMM, [4096][768] B).
    ushort_t* W1P = (ushort_t*)alloc((size_t)PSZ * 2);
    ushort_t* W3P = (ushort_t*)alloc((size_t)PSZ * 2);
    ushort_t* W2P = (ushort_t*)alloc((size_t)PSZ * 2);
    // region below is reused late as bf16 out_w (52 MB >= 49.15 MB)
    ushort_t* QKB = (ushort_t*)alloc((size_t)SEQL * QKS * 2);   // fused Q|K [2048][1536]
    ushort_t* VTG = (ushort_t*)alloc((size_t)SEQL * DIMC * 2);  // V^T [DIMC][SEQL]
    ushort_t* AO  = (ushort_t*)alloc((size_t)SEQL * DIMC * 2);
    float*    Y13 = (float*)   alloc((size_t)SEQL * 4096 * 4);  // [2048][4096] y1|y3
    ushort_t* HS  = (ushort_t*)alloc((size_t)SEQL * HIDP * 2);
    ushort_t* OUTWB = QKB;  // aliased, used only after last layer

    embed_kernel<<<1536, 256, 0, stream>>>(tok, emb, H);

    for (int l = 0; l < 4; ++l) {
        conv_layer_kernel<<<27648, 256, 0, stream>>>(
            wq + (size_t)l * QSZ, wk + (size_t)l * QSZ, wv + (size_t)l * QSZ, wo + (size_t)l * QSZ,
            w1 + (size_t)l * W2SRC, w2 + (size_t)l * W2SRC, w3 + (size_t)l * W2SRC,
            WQB, WKB, WVB, WOB, W1P, W3P, W2P);

        rmsnorm_kernel<<<512, 256, 0, stream>>>(H, anw + (size_t)l * DIMC, XN);

        // fused Q|K projection: M=2048 N=1536 K=768 -> QKB bf16
        gemm_lds_kernel<128,128,1><<<dim3(16,12), 256, 0, stream>>>(XN, DIMC, WQB, DIMC, QKB, QKS, DIMC);
        // V^T projection (swapped operands): C[d][s] = sum_k Wv[d][k] X[s][k]
        gemm_lds_kernel<64,128,1><<<dim3(12,16), 256, 0, stream>>>(WVB, DIMC, XN, DIMC, VTG, SEQL, DIMC);

        rope_kernel<<<6144, 256, 0, stream>>>(QKB);   // Q and K in one pass

        attn_mfma_kernel<<<dim3(32, NHEAD), 256, 0, stream>>>(QKB, QKB + 768, VTG, AO, QKS);

        // o @ wo^T, accumulate into H (residual): M=2048 N=768
        gemm_lds_kernel<128,64,2><<<dim3(16,12), 256, 0, stream>>>(AO, DIMC, WOB, DIMC, H, DIMC, DIMC);

        rmsnorm_kernel<<<512, 256, 0, stream>>>(H, fnw + (size_t)l * DIMC, YN);

        // FFN up, FUSED w1|w3: M=2048 N=4096 K=768
        gemm_lds_kernel<128,128,0><<<dim3(16,32), 256, 0, stream>>>(YN, DIMC, W1P, DIMC, Y13, 4096, DIMC);

        silu_mul_kernel<<<4096, 256, 0, stream>>>(Y13, HS);

        // FFN down: M=2048 N=768 K=2048(pad), accumulate into H
        gemm_lds_kernel<128,64,2><<<dim3(16,12), 256, 0, stream>>>(HS, HIDP, W2P, HIDP, H, DIMC, HIDP);
    }

    rmsnorm_kernel<<<512, 256, 0, stream>>>(H, nw, XN);
    conv_outw_kernel<<<24000, 256, 0, stream>>>(outw, OUTWB);
    // logits: M=2048 N=32000 K=768, f32 out
    gemm_lds_kernel<128,128,0><<<dim3(16,250), 256, 0, stream>>>(XN, DIMC, OUTWB, DIMC, out, NVOCAB, DIMC);
}

// Round 5
// 1304.698 us; speedup vs baseline: 1.8458x; 1.0316x over previous
//
#include <hip/hip_runtime.h>
#include <math.h>

typedef unsigned int uint32;
typedef unsigned short ushort_t;

typedef __attribute__((ext_vector_type(8))) short short8;
typedef __attribute__((ext_vector_type(4))) float floatx4;

#define SEQL 2048
#define DIMC 768
#define NHEAD 12
#define HDIM 64
#define HIDV 2042
#define HIDP 2048
#define NVOCAB 32000
#define QKS 1536             // fused Q|K row stride
#define QSZ (DIMC*DIMC)      // 589824
#define PSZ (HIDP*DIMC)      // 1572864
#define W2SRC (DIMC*HIDV)    // 1568256

__device__ __forceinline__ ushort_t f2bf(float f) {
    uint32 u = __float_as_uint(f);
    u += 0x7FFFu + ((u >> 16) & 1u);   // round-to-nearest-even
    return (ushort_t)(u >> 16);
}
__device__ __forceinline__ float bf2f(ushort_t h) {
    return __uint_as_float(((uint32)h) << 16);
}

union Frag { short8 s8; uint32 u[4]; ushort_t us[8]; };

// async global->LDS 16B copy (dest must be linear in lane order within wave)
#define GLOAD_LDS16(g, l) \
    __builtin_amdgcn_global_load_lds((const __attribute__((address_space(1))) void*)(g), \
                                     (__attribute__((address_space(3))) void*)(l), 16, 0, 0)

// ---------------- LDS-staged GEMM, double-buffered 2-phase, XCD-swizzled ---
// C[M,N] (=|+=) A[M,K] * B[N,K]^T, bf16 in. BM,BN in {64,128}; 4 waves (2x2),
// wave tile (BM/2)x(BN/2). stage(t+1) issues before compute(t); single
// __syncthreads per iter drains vmcnt (prefetch flight overlaps MFMA).
// Block swizzle: bijective XCD chunking (requires gridDim.x*gridDim.y % 8 == 0).
// OUTMODE: 0 = store f32, 1 = store bf16, 2 = accumulate into f32 (residual)
template<int BM, int BN, int OUTMODE>
__global__ __launch_bounds__(256)
void gemm_lds_kernel(const ushort_t* __restrict__ A, int lda,
                     const ushort_t* __restrict__ B, int ldb,
                     void* __restrict__ C, int ldc, int K)
{
    constexpr int WTM = BM / 32;
    constexpr int WTN = BN / 32;
    __shared__ __align__(16) ushort_t As[2][BM * 32];
    __shared__ __align__(16) ushort_t Bs[2][BN * 32];

    const int tid = threadIdx.x;
    // bijective XCD swizzle: lid = xcd*(nwg/8) + pos
    const int nwg  = gridDim.x * gridDim.y;
    const int lid0 = blockIdx.y * gridDim.x + blockIdx.x;
    const int lid  = (lid0 & 7) * (nwg >> 3) + (lid0 >> 3);
    const int bx = lid % gridDim.x;
    const int by = lid / gridDim.x;

    const int wid = tid >> 6, lane = tid & 63;
    const int wm = wid & 1, wn = wid >> 1;
    const int r = lane & 15, quad = lane >> 4;
    const int m0 = bx * BM;
    const int n0 = by * BN;

    floatx4 acc[WTM][WTN];
#pragma unroll
    for (int i = 0; i < WTM; ++i)
#pragma unroll
        for (int j = 0; j < WTN; ++j) acc[i][j] = (floatx4){0.f, 0.f, 0.f, 0.f};

    const int row_a = tid >> 2;          // 0..63
    const int col8  = (tid & 3) * 8;
    const ushort_t* gA = A + (size_t)(m0 + row_a) * lda + col8;
    const ushort_t* gB = B + (size_t)(n0 + row_a) * ldb + col8;

    auto stage = [&](int buf, int k0) {
        GLOAD_LDS16(gA + k0, &As[buf][(size_t)tid * 8]);
        if (BM == 128) GLOAD_LDS16(gA + (size_t)64 * lda + k0, &As[buf][(size_t)(tid + 256) * 8]);
        GLOAD_LDS16(gB + k0, &Bs[buf][(size_t)tid * 8]);
        if (BN == 128) GLOAD_LDS16(gB + (size_t)64 * ldb + k0, &Bs[buf][(size_t)(tid + 256) * 8]);
    };

    stage(0, 0);
    __syncthreads();
    int buf = 0;
    for (int k0 = 0; k0 < K; k0 += 32) {
        if (k0 + 32 < K) stage(buf ^ 1, k0 + 32);   // prefetch overlaps MFMA below
        const ushort_t* pa = &As[buf][(wm * (BM / 2) + r) * 32 + quad * 8];
        const ushort_t* pb = &Bs[buf][(wn * (BN / 2) + r) * 32 + quad * 8];
        short8 af[WTM], bf[WTN];
#pragma unroll
        for (int i = 0; i < WTM; ++i) af[i] = *(const short8*)(pa + i * 16 * 32);
#pragma unroll
        for (int j = 0; j < WTN; ++j) bf[j] = *(const short8*)(pb + j * 16 * 32);
#pragma unroll
        for (int i = 0; i < WTM; ++i)
#pragma unroll
            for (int j = 0; j < WTN; ++j)
                acc[i][j] = __builtin_amdgcn_mfma_f32_16x16x32_bf16(af[i], bf[j], acc[i][j], 0, 0, 0);
        __syncthreads();   // drains prefetch + protects buf for next overwrite
        buf ^= 1;
    }

#pragma unroll
    for (int i = 0; i < WTM; ++i) {
        const int row = m0 + wm * (BM / 2) + i * 16 + quad * 4;
#pragma unroll
        for (int j = 0; j < WTN; ++j) {
            const int col = n0 + wn * (BN / 2) + j * 16 + r;
#pragma unroll
            for (int t = 0; t < 4; ++t) {
                const size_t off = (size_t)(row + t) * ldc + col;
                const float v = acc[i][j][t];
                if (OUTMODE == 2)      ((float*)C)[off] += v;
                else if (OUTMODE == 1) ((ushort_t*)C)[off] = f2bf(v);
                else                   ((float*)C)[off] = v;
            }
        }
    }
}

// ---------------- RMSNorm: fp32 in -> bf16 out, one wave per row -----------
__global__ __launch_bounds__(256)
void rmsnorm_kernel(const float* __restrict__ x, const float* __restrict__ g,
                    ushort_t* __restrict__ out)
{
    const int w = threadIdx.x >> 6, lane = threadIdx.x & 63;
    const int row = blockIdx.x * 4 + w;
    const float* xr = x + (size_t)row * DIMC;
    float4 a = *(const float4*)(xr + lane * 4);
    float4 b = *(const float4*)(xr + 256 + lane * 4);
    float4 c = *(const float4*)(xr + 512 + lane * 4);
    float ss = a.x*a.x + a.y*a.y + a.z*a.z + a.w*a.w
             + b.x*b.x + b.y*b.y + b.z*b.z + b.w*b.w
             + c.x*c.x + c.y*c.y + c.z*c.z + c.w*c.w;
#pragma unroll
    for (int off = 32; off > 0; off >>= 1) ss += __shfl_xor(ss, off, 64);
    const float inv = rsqrtf(ss * (1.0f / DIMC) + 1e-6f);
    float4 ga = *(const float4*)(g + lane * 4);
    float4 gb = *(const float4*)(g + 256 + lane * 4);
    float4 gc = *(const float4*)(g + 512 + lane * 4);
    ushort_t* orow = out + (size_t)row * DIMC;
    *(ushort4*)(orow + lane * 4)       = make_ushort4(f2bf(a.x*inv*ga.x), f2bf(a.y*inv*ga.y), f2bf(a.z*inv*ga.z), f2bf(a.w*inv*ga.w));
    *(ushort4*)(orow + 256 + lane * 4) = make_ushort4(f2bf(b.x*inv*gb.x), f2bf(b.y*inv*gb.y), f2bf(b.z*inv*gb.z), f2bf(b.w*inv*gb.w));
    *(ushort4*)(orow + 512 + lane * 4) = make_ushort4(f2bf(c.x*inv*gc.x), f2bf(c.y*inv*gc.y), f2bf(c.z*inv*gc.z), f2bf(c.w*inv*gc.w));
}

// ---------------- RoPE in-place on fused QK [S][24*64] ---------------------
__global__ __launch_bounds__(256)
void rope_kernel(ushort_t* __restrict__ x)
{
    const int idx = blockIdx.x * 256 + threadIdx.x;
    const int j = idx & 31;
    const int h = (idx >> 5) % 24;
    const int s = idx / 768;
    const float freq = expf(-0.28782313662425574f * (float)j);
    const float ang = (float)s * freq;
    const float sn = sinf(ang), cs = cosf(ang);
    ushort_t* p = x + (size_t)s * QKS + h * HDIM + 2 * j;
    const float a = bf2f(p[0]), b = bf2f(p[1]);
    p[0] = f2bf(a * cs - b * sn);
    p[1] = f2bf(a * sn + b * cs);
}

// ---------------- MFMA flash attention, LDS-staged K/V, KVBLK=128 ----------
// Block = 4 waves = 64 q rows. Per 128-key chunk: cooperative gload_lds
// staging of K[128x64] and V^T[64x128] (double-buffered, XOR-swizzled via
// pre-swizzled global source), 16 QK MFMA + ONE softmax round + 16 PV MFMA
// per wave. nit=(bx+2)>>1 chunks; only final chunk causal-masked. KVBLK=128
// halves softmax reduce rounds / O-rescales / barriers per key vs KVBLK=64.
__global__ __launch_bounds__(256)
void attn_mfma_kernel(const ushort_t* __restrict__ Q, const ushort_t* __restrict__ K,
                      const ushort_t* __restrict__ VT, ushort_t* __restrict__ O,
                      int qks)
{
    __shared__ __align__(16) ushort_t Ks[2][128 * 64];   // [key][d], swizzled rows (128B)
    __shared__ __align__(16) ushort_t Vs[2][64 * 128];   // [d][key], swizzled rows (256B)

    const int tid = threadIdx.x;
    const int w = tid >> 6, lane = tid & 63;
    const int r = lane & 15, quad = lane >> 4;
    const int hb = blockIdx.y * HDIM;
    const int bx = 31 - (int)blockIdx.x;      // longest-first dispatch
    const int qb = bx * 64 + w * 16;          // wave q start
    const int nit = (bx + 2) >> 1;            // 128-key chunks

    // K staging: 1024 16B chunks; thread t owns c = t + 256*i (i=0..3).
    // chunk c: row=c>>3, slot=c&7; source col elem = (slot^(row&7))*8
    const int krow = tid >> 3;                            // rows krow + 32*i
    const int kcol = ((tid & 7) ^ (krow & 7)) << 3;
    // V staging: chunk c: row=c>>4, slot=c&15; source col elem = (slot^(row&7))*8
    const int vrow = tid >> 4;                            // rows vrow + 16*i
    const int vcol = (((tid & 15) ^ (vrow & 7))) << 3;
    const int swz = (r & 7) << 4;                         // read-side byte XOR

    // Q fragments (B operand): B[n=r][k=quad*8+j] = Q[qb+r][hb+f*32+quad*8+j] * 1/8
    Frag bq[2];
    {
        const ushort_t* qp = Q + (size_t)(qb + r) * qks + hb + quad * 8;
#pragma unroll
        for (int fi = 0; fi < 2; ++fi) {
            Frag t; t.s8 = *(const short8*)(qp + fi * 32);
#pragma unroll
            for (int e = 0; e < 8; ++e) t.us[e] = f2bf(bf2f(t.us[e]) * 0.125f);
            bq[fi] = t;
        }
    }

    floatx4 o[4];
#pragma unroll
    for (int dg = 0; dg < 4; ++dg) o[dg] = (floatx4){0.f, 0.f, 0.f, 0.f};
    float m = -INFINITY, l = 0.f;

    auto stage = [&](int buf, int kc) {
        const ushort_t* kg = K + (size_t)(kc + krow) * qks + hb + kcol;
        GLOAD_LDS16(kg,                      &Ks[buf][(size_t)tid * 8]);
        GLOAD_LDS16(kg + (size_t)32 * qks,   &Ks[buf][(size_t)(tid + 256) * 8]);
        GLOAD_LDS16(kg + (size_t)64 * qks,   &Ks[buf][(size_t)(tid + 512) * 8]);
        GLOAD_LDS16(kg + (size_t)96 * qks,   &Ks[buf][(size_t)(tid + 768) * 8]);
        const ushort_t* vg = VT + (size_t)(hb + vrow) * SEQL + kc + vcol;
        GLOAD_LDS16(vg,                      &Vs[buf][(size_t)tid * 8]);
        GLOAD_LDS16(vg + (size_t)16 * SEQL,  &Vs[buf][(size_t)(tid + 256) * 8]);
        GLOAD_LDS16(vg + (size_t)32 * SEQL,  &Vs[buf][(size_t)(tid + 512) * 8]);
        GLOAD_LDS16(vg + (size_t)48 * SEQL,  &Vs[buf][(size_t)(tid + 768) * 8]);
    };

    stage(0, 0);
    __syncthreads();

    for (int it = 0; it < nit; ++it) {
        const int buf = it & 1;
        const int kc = it * 128;
        if (it + 1 < nit) stage(buf ^ 1, kc + 128);

        const char* ksb = (const char*)Ks[buf];
        const char* vsb = (const char*)Vs[buf];

        // QK^T: st[s][tt] = score(key kc+s*16+quad*4+tt, q=qb+r)
        floatx4 st[8];
        __builtin_amdgcn_s_setprio(1);
#pragma unroll
        for (int s = 0; s < 8; ++s) {
            st[s] = (floatx4){0.f, 0.f, 0.f, 0.f};
#pragma unroll
            for (int f = 0; f < 2; ++f) {
                const int lb = (s * 16 + r) * 128 + ((f * 64 + quad * 16) ^ swz);
                const short8 a = *(const short8*)(ksb + lb);
                st[s] = __builtin_amdgcn_mfma_f32_16x16x32_bf16(a, bq[f].s8, st[s], 0, 0, 0);
            }
        }
        __builtin_amdgcn_s_setprio(0);

        if (it == nit - 1) {   // causal mask, only final chunk
            const int q = qb + r;
#pragma unroll
            for (int s = 0; s < 8; ++s)
#pragma unroll
                for (int tt = 0; tt < 4; ++tt)
                    if (kc + s * 16 + quad * 4 + tt > q) st[s][tt] = -INFINITY;
        }

        // online softmax: ONE round per 128 keys
        float vm = -INFINITY;
#pragma unroll
        for (int s = 0; s < 8; ++s)
            vm = fmaxf(vm, fmaxf(fmaxf(st[s][0], st[s][1]), fmaxf(st[s][2], st[s][3])));
        vm = fmaxf(vm, __shfl_xor(vm, 16, 64));
        vm = fmaxf(vm, __shfl_xor(vm, 32, 64));
        const float mnew = fmaxf(m, vm);
        const float alpha = __expf(m - mnew);
        float ps = 0.f;
#pragma unroll
        for (int s = 0; s < 8; ++s)
#pragma unroll
            for (int tt = 0; tt < 4; ++tt) {
                st[s][tt] = __expf(st[s][tt] - mnew);   // P in-place
                ps += st[s][tt];
            }
        ps += __shfl_xor(ps, 16, 64);
        ps += __shfl_xor(ps, 32, 64);
        l = l * alpha + ps;
        m = mnew;

        // P fragments (B operand): ap[ks] covers keys kc+ks*32..+31
        Frag ap[4];
#pragma unroll
        for (int ks = 0; ks < 4; ++ks) {
            ap[ks].u[0] = (uint32)f2bf(st[2*ks][0])   | ((uint32)f2bf(st[2*ks][1])   << 16);
            ap[ks].u[1] = (uint32)f2bf(st[2*ks][2])   | ((uint32)f2bf(st[2*ks][3])   << 16);
            ap[ks].u[2] = (uint32)f2bf(st[2*ks+1][0]) | ((uint32)f2bf(st[2*ks+1][1]) << 16);
            ap[ks].u[3] = (uint32)f2bf(st[2*ks+1][2]) | ((uint32)f2bf(st[2*ks+1][3]) << 16);
        }

        // PV: o[dg] += V^T slices x P slices (4 key-slices of 32)
        __builtin_amdgcn_s_setprio(1);
#pragma unroll
        for (int dg = 0; dg < 4; ++dg) {
            const int rowb = (dg * 16 + r) * 256;
            o[dg] *= alpha;
#pragma unroll
            for (int ks = 0; ks < 4; ++ks) {
                Frag av;
                *(uint2*)&av.u[0] = *(const uint2*)(vsb + rowb + ((ks * 64 + quad * 8) ^ swz));
                *(uint2*)&av.u[2] = *(const uint2*)(vsb + rowb + ((ks * 64 + 32 + quad * 8) ^ swz));
                o[dg] = __builtin_amdgcn_mfma_f32_16x16x32_bf16(av.s8, ap[ks].s8, o[dg], 0, 0, 0);
            }
        }
        __builtin_amdgcn_s_setprio(0);

        __syncthreads();   // drains next-chunk staging; all waves done with buf
    }

    // write O: lane holds O^T[d=dg*16+quad*4+t][q=qb+r]
    const float inv = 1.0f / l;
    ushort_t* op = O + (size_t)(qb + r) * DIMC + hb + quad * 4;
#pragma unroll
    for (int dg = 0; dg < 4; ++dg) {
        uint2 pkd;
        pkd.x = (uint32)f2bf(o[dg][0] * inv) | ((uint32)f2bf(o[dg][1] * inv) << 16);
        pkd.y = (uint32)f2bf(o[dg][2] * inv) | ((uint32)f2bf(o[dg][3] * inv) << 16);
        *(uint2*)(op + dg * 16) = pkd;
    }
}

// ---------------- SiLU(y1) * y3 -> bf16, Y13 bf16 layout [2048][4096] ------
// cols 0..2047 = y1, cols 2048..4095 = y3 (padded cols give silu(0)*0 = 0)
__global__ __launch_bounds__(256)
void silu_mul_kernel(const ushort_t* __restrict__ y13, ushort_t* __restrict__ hs)
{
    const int idx = blockIdx.x * 256 + threadIdx.x;   // 2048*256
    const int s = idx >> 8;
    const int c = (idx & 255) * 8;
    const ushort_t* row = y13 + (size_t)s * 4096;
    short8 a8 = *(const short8*)(row + c);
    short8 b8 = *(const short8*)(row + 2048 + c);
    ushort_t ov[8];
#pragma unroll
    for (int e = 0; e < 8; ++e) {
        const float a = bf2f((ushort_t)a8[e]);
        const float b = bf2f((ushort_t)b8[e]);
        ov[e] = f2bf(a / (1.f + __expf(-a)) * b);
    }
    short8 pk;
#pragma unroll
    for (int e = 0; e < 8; ++e) pk[e] = (short)ov[e];
    *(short8*)(hs + (size_t)s * HIDP + c) = pk;
}

// ---------------- Embedding gather (fp32) ----------------------------------
__global__ __launch_bounds__(256)
void embed_kernel(const int* __restrict__ tok, const float* __restrict__ emb,
                  float* __restrict__ h)
{
    const int idx = blockIdx.x * 256 + threadIdx.x;    // SEQL*192
    const int s = idx / 192, c = (idx % 192) * 4;
    const int t = tok[s];
    *(float4*)(h + (size_t)s * DIMC + c) = *(const float4*)(emb + (size_t)t * DIMC + c);
}

// ---------------- Per-layer weight conversion fp32 -> bf16 (with padding) --
__global__ __launch_bounds__(256)
void conv_layer_kernel(const float* __restrict__ wq, const float* __restrict__ wk,
                       const float* __restrict__ wv, const float* __restrict__ wo,
                       const float* __restrict__ w1, const float* __restrict__ w2,
                       const float* __restrict__ w3,
                       ushort_t* __restrict__ wqb, ushort_t* __restrict__ wkb,
                       ushort_t* __restrict__ wvb, ushort_t* __restrict__ wob,
                       ushort_t* __restrict__ w1p, ushort_t* __restrict__ w3p,
                       ushort_t* __restrict__ w2p)
{
    int idx = blockIdx.x * 256 + threadIdx.x;
    if (idx < 4 * QSZ) {
        const int m = idx / QSZ, i = idx - m * QSZ;
        const float* s = (m == 0) ? wq : (m == 1) ? wk : (m == 2) ? wv : wo;
        ushort_t*   d = (m == 0) ? wqb : (m == 1) ? wkb : (m == 2) ? wvb : wob;
        d[i] = f2bf(s[i]);
        return;
    }
    idx -= 4 * QSZ;
    if (idx < PSZ) {   // w1 padded: [2048][768], rows >= 2042 zero
        const int n = idx / DIMC, kk = idx - n * DIMC;
        w1p[idx] = (n < HIDV) ? f2bf(w1[(size_t)n * DIMC + kk]) : (ushort_t)0;
        return;
    }
    idx -= PSZ;
    if (idx < PSZ) {
        const int n = idx / DIMC, kk = idx - n * DIMC;
        w3p[idx] = (n < HIDV) ? f2bf(w3[(size_t)n * DIMC + kk]) : (ushort_t)0;
        return;
    }
    idx -= PSZ;
    if (idx < PSZ) {   // w2 padded: [768][2048], cols >= 2042 zero
        const int n = idx >> 11, kk = idx & 2047;
        w2p[idx] = (kk < HIDV) ? f2bf(w2[(size_t)n * HIDV + kk]) : (ushort_t)0;
        return;
    }
}

// ---------------- out_w conversion fp32 -> bf16 ----------------------------
__global__ __launch_bounds__(256)
void conv_outw_kernel(const float* __restrict__ src, ushort_t* __restrict__ dst)
{
    const size_t idx = (size_t)(blockIdx.x * 256 + threadIdx.x);
    float4 a = *(const float4*)(src + idx * 4);
    *(ushort4*)(dst + idx * 4) = make_ushort4(f2bf(a.x), f2bf(a.y), f2bf(a.z), f2bf(a.w));
}

extern "C" void kernel_launch(void* const* d_in, const int* in_sizes, int n_in,
                              void* d_out, int out_size, void* d_ws, size_t ws_size,
                              hipStream_t stream)
{
    const int*   tok  = (const int*)d_in[0];
    const float* emb  = (const float*)d_in[1];
    const float* wq   = (const float*)d_in[2];
    const float* wk   = (const float*)d_in[3];
    const float* wv   = (const float*)d_in[4];
    const float* wo   = (const float*)d_in[5];
    const float* w1   = (const float*)d_in[6];
    const float* w2   = (const float*)d_in[7];
    const float* w3   = (const float*)d_in[8];
    const float* anw  = (const float*)d_in[9];
    const float* fnw  = (const float*)d_in[10];
    const float* nw   = (const float*)d_in[11];
    const float* outw = (const float*)d_in[12];
    float* out = (float*)d_out;
    (void)in_sizes; (void)n_in; (void)out_size; (void)ws_size;

    char* p = (char*)d_ws;
    auto alloc = [&](size_t bytes) { char* r = p; p += (bytes + 255) & ~(size_t)255; return r; };
    float*    H   = (float*)   alloc((size_t)SEQL * DIMC * 4);
    ushort_t* XN  = (ushort_t*)alloc((size_t)SEQL * DIMC * 2);
    ushort_t* YN  = (ushort_t*)alloc((size_t)SEQL * DIMC * 2);
    // WQB and WKB MUST stay adjacent: fused QK GEMM treats them as one
    // [1536][768] B matrix (QSZ*2 bytes is 256-aligned so no gap).
    ushort_t* WQB = (ushort_t*)alloc((size_t)QSZ * 2);
    ushort_t* WKB = (ushort_t*)alloc((size_t)QSZ * 2);
    ushort_t* WVB = (ushort_t*)alloc((size_t)QSZ * 2);
    ushort_t* WOB = (ushort_t*)alloc((size_t)QSZ * 2);
    // W1P and W3P MUST stay adjacent (fused FFN-up GEMM, [4096][768] B).
    ushort_t* W1P = (ushort_t*)alloc((size_t)PSZ * 2);
    ushort_t* W3P = (ushort_t*)alloc((size_t)PSZ * 2);
    ushort_t* W2P = (ushort_t*)alloc((size_t)PSZ * 2);
    // region below is reused late as bf16 out_w (>= 49.15 MB)
    ushort_t* QKB = (ushort_t*)alloc((size_t)SEQL * QKS * 2);   // fused Q|K [2048][1536]
    ushort_t* VTG = (ushort_t*)alloc((size_t)SEQL * DIMC * 2);  // V^T [DIMC][SEQL]
    ushort_t* AO  = (ushort_t*)alloc((size_t)SEQL * DIMC * 2);
    ushort_t* Y13 = (ushort_t*)alloc((size_t)SEQL * 4096 * 2);  // [2048][4096] y1|y3 bf16
    ushort_t* HS  = (ushort_t*)alloc((size_t)SEQL * HIDP * 2);
    ushort_t* OUTWB = QKB;  // aliased, used only after last layer

    embed_kernel<<<1536, 256, 0, stream>>>(tok, emb, H);

    for (int l = 0; l < 4; ++l) {
        conv_layer_kernel<<<27648, 256, 0, stream>>>(
            wq + (size_t)l * QSZ, wk + (size_t)l * QSZ, wv + (size_t)l * QSZ, wo + (size_t)l * QSZ,
            w1 + (size_t)l * W2SRC, w2 + (size_t)l * W2SRC, w3 + (size_t)l * W2SRC,
            WQB, WKB, WVB, WOB, W1P, W3P, W2P);

        rmsnorm_kernel<<<512, 256, 0, stream>>>(H, anw + (size_t)l * DIMC, XN);

        // fused Q|K projection: M=2048 N=1536 K=768 -> QKB bf16
        gemm_lds_kernel<128,128,1><<<dim3(16,12), 256, 0, stream>>>(XN, DIMC, WQB, DIMC, QKB, QKS, DIMC);
        // V^T projection (swapped operands): C[d][s] = sum_k Wv[d][k] X[s][k]
        gemm_lds_kernel<64,128,1><<<dim3(12,16), 256, 0, stream>>>(WVB, DIMC, XN, DIMC, VTG, SEQL, DIMC);

        rope_kernel<<<6144, 256, 0, stream>>>(QKB);   // Q and K in one pass

        attn_mfma_kernel<<<dim3(32, NHEAD), 256, 0, stream>>>(QKB, QKB + 768, VTG, AO, QKS);

        // o @ wo^T, accumulate into H (residual): M=2048 N=768
        gemm_lds_kernel<128,64,2><<<dim3(16,12), 256, 0, stream>>>(AO, DIMC, WOB, DIMC, H, DIMC, DIMC);

        rmsnorm_kernel<<<512, 256, 0, stream>>>(H, fnw + (size_t)l * DIMC, YN);

        // FFN up, FUSED w1|w3: M=2048 N=4096 K=768, bf16 out
        gemm_lds_kernel<128,128,1><<<dim3(16,32), 256, 0, stream>>>(YN, DIMC, W1P, DIMC, Y13, 4096, DIMC);

        silu_mul_kernel<<<2048, 256, 0, stream>>>(Y13, HS);

        // FFN down: M=2048 N=768 K=2048(pad), accumulate into H
        gemm_lds_kernel<128,64,2><<<dim3(16,12), 256, 0, stream>>>(HS, HIDP, W2P, HIDP, H, DIMC, HIDP);
    }

    rmsnorm_kernel<<<512, 256, 0, stream>>>(H, nw, XN);
    conv_outw_kernel<<<24000, 256, 0, stream>>>(outw, OUTWB);
    // logits: M=2048 N=32000 K=768, f32 out
    gemm_lds_kernel<128,128,0><<<dim3(16,250), 256, 0, stream>>>(XN, DIMC, OUTWB, DIMC, out, NVOCAB, DIMC);
}